// Round 1
// baseline (6418.466 us; speedup 1.0000x reference)
//
#include <hip/hip_runtime.h>
#include <math.h>

#define NN 100000
#define NE 1600000
#define FIN 128
#define HD 64
#define NB 256
#define NEGF (-1e30f)

// ---------------- graph offsets ----------------
__global__ void k_hist(const int* __restrict__ batch, int* __restrict__ counts) {
    int i = blockIdx.x * 256 + threadIdx.x;
    if (i < NN) atomicAdd(&counts[batch[i]], 1);
}
__global__ void k_offs(const int* __restrict__ counts, int* __restrict__ offs) {
    int acc = 0;
    for (int g = 0; g < NB; ++g) { offs[g] = acc; acc += counts[g]; }
    offs[NB] = acc;
}

// ---------------- GIN aggregation (scatter-add) ----------------
__global__ void k_scatter128(const float* __restrict__ x, const int* __restrict__ src,
                             const int* __restrict__ dst, float* __restrict__ agg) {
    int t = blockIdx.x * 256 + threadIdx.x;
    if (t >= NE * 32) return;
    int e = t >> 5, q = t & 31;
    int s = src[e], d = dst[e];
    float4 v = reinterpret_cast<const float4*>(x)[(size_t)s * 32 + q];
    float* p = agg + (size_t)d * 128 + q * 4;
    atomicAdd(p + 0, v.x); atomicAdd(p + 1, v.y);
    atomicAdd(p + 2, v.z); atomicAdd(p + 3, v.w);
}
__global__ void k_scatter64(const float* __restrict__ x, const int* __restrict__ src,
                            const int* __restrict__ dst, const float* __restrict__ keepm,
                            float* __restrict__ agg) {
    int t = blockIdx.x * 256 + threadIdx.x;
    if (t >= NE * 16) return;
    int e = t >> 4, q = t & 15;
    int s = src[e], d = dst[e];
    if (keepm[s] == 0.f || keepm[d] == 0.f) return;
    float4 v = reinterpret_cast<const float4*>(x)[(size_t)s * 16 + q];
    float* p = agg + (size_t)d * 64 + q * 4;
    atomicAdd(p + 0, v.x); atomicAdd(p + 1, v.y);
    atomicAdd(p + 2, v.z); atomicAdd(p + 3, v.w);
}

// ---------------- MLP layers (relu((a[+agg]) @ W + b)) ----------------
__global__ void k_mm128(const float* __restrict__ x, const float* __restrict__ agg,
                        const float* __restrict__ W, const float* __restrict__ b,
                        float* __restrict__ out) {
    __shared__ float row[4][128];
    int n0 = blockIdx.x * 4, tid = threadIdx.x;
    for (int i = tid; i < 512; i += 256) {
        int r = i >> 7, c = i & 127;
        size_t idx = (size_t)(n0 + r) * 128 + c;
        row[r][c] = x[idx] + agg[idx];
    }
    __syncthreads();
    int r = tid >> 6, f = tid & 63;
    float acc = b[f];
#pragma unroll 8
    for (int k = 0; k < 128; ++k) acc += row[r][k] * W[k * 64 + f];
    out[(size_t)(n0 + r) * 64 + f] = fmaxf(acc, 0.f);
}
__global__ void k_mm64(const float* __restrict__ a, const float* __restrict__ agg,
                       const float* __restrict__ W, const float* __restrict__ b,
                       float* __restrict__ out) {
    __shared__ float row[4][64];
    int n0 = blockIdx.x * 4, tid = threadIdx.x;
    int r = tid >> 6, f = tid & 63;
    size_t idx = (size_t)(n0 + r) * 64 + f;
    float v = a[idx];
    if (agg) v += agg[idx];
    row[r][f] = v;
    __syncthreads();
    float acc = b[f];
#pragma unroll 8
    for (int k = 0; k < 64; ++k) acc += row[r][k] * W[k * 64 + f];
    out[idx] = fmaxf(acc, 0.f);
}

// ---------------- SAG pool pieces ----------------
__global__ void k_dot_gw(const float* __restrict__ h, const float* __restrict__ gW,
                         float* __restrict__ hw) {
    int tid = threadIdx.x;
    int n = blockIdx.x * 4 + (tid >> 6), f = tid & 63;
    float v = h[(size_t)n * 64 + f] * gW[f];
    for (int o = 32; o > 0; o >>= 1) v += __shfl_down(v, o, 64);
    if (f == 0) hw[n] = v;
}
__global__ void k_indeg(const int* __restrict__ dst, int* __restrict__ indeg) {
    int e = blockIdx.x * 256 + threadIdx.x;
    if (e < NE) atomicAdd(&indeg[dst[e]], 1);
}
__global__ void k_dinv1(const int* __restrict__ indeg, float* __restrict__ dinv) {
    int i = blockIdx.x * 256 + threadIdx.x;
    if (i < NN) dinv[i] = 1.f / sqrtf((float)indeg[i] + 1.0f);
}
__global__ void k_deg2(const int* __restrict__ src, const int* __restrict__ dst,
                       const float* __restrict__ keep1, float* __restrict__ degf) {
    int e = blockIdx.x * 256 + threadIdx.x;
    if (e >= NE) return;
    float w = keep1[src[e]] * keep1[dst[e]];
    if (w > 0.f) atomicAdd(&degf[dst[e]], w);
}
__global__ void k_dinv2(const float* __restrict__ degf, const float* __restrict__ keep1,
                        float* __restrict__ dinv) {
    int i = blockIdx.x * 256 + threadIdx.x;
    if (i >= NN) return;
    float deg = degf[i] + keep1[i];
    dinv[i] = (deg > 0.f) ? 1.f / sqrtf(fmaxf(deg, 1e-12f)) : 0.f;
}
__global__ void k_attn_edge(const int* __restrict__ src, const int* __restrict__ dst,
                            const float* __restrict__ hw, const float* __restrict__ dinv,
                            const float* __restrict__ keepm, float* __restrict__ attn) {
    int e = blockIdx.x * 256 + threadIdx.x;
    if (e >= NE) return;
    int s = src[e], d = dst[e];
    if (keepm && (keepm[s] == 0.f || keepm[d] == 0.f)) return;
    atomicAdd(&attn[d], hw[s] * dinv[s] * dinv[d]);
}
__global__ void k_attn_self(float* __restrict__ attn, const float* __restrict__ hw,
                            const float* __restrict__ dinv, const float* __restrict__ nmask,
                            const float* __restrict__ gb) {
    int i = blockIdx.x * 256 + threadIdx.x;
    if (i >= NN) return;
    float nm = nmask ? nmask[i] : 1.f;
    attn[i] += hw[i] * dinv[i] * dinv[i] * nm + gb[0];
}
__global__ void k_softmax_pool(const float* __restrict__ attn, const float* __restrict__ nmask,
                               const int* __restrict__ offs, float* __restrict__ score,
                               float* __restrict__ keep) {
    int b = blockIdx.x, tid = threadIdx.x;
    int s0 = offs[b], s1 = offs[b + 1];
    __shared__ float red[256];
    // segment max of attn over unmasked
    float m = NEGF;
    for (int i = s0 + tid; i < s1; i += 256) {
        float nm = nmask ? nmask[i] : 1.f;
        if (nm > 0.f) m = fmaxf(m, attn[i]);
    }
    red[tid] = m; __syncthreads();
    for (int o = 128; o > 0; o >>= 1) { if (tid < o) red[tid] = fmaxf(red[tid], red[tid + o]); __syncthreads(); }
    m = red[0]; __syncthreads();
    // segment sum of exp
    float s = 0.f;
    for (int i = s0 + tid; i < s1; i += 256) {
        float nm = nmask ? nmask[i] : 1.f;
        if (nm > 0.f) s += expf(attn[i] - m);
    }
    red[tid] = s; __syncthreads();
    for (int o = 128; o > 0; o >>= 1) { if (tid < o) red[tid] += red[tid + o]; __syncthreads(); }
    s = red[0]; __syncthreads();
    float sden = fmaxf(s, 1e-30f);
    // scores + segment max of score
    float smax = NEGF;
    for (int i = s0 + tid; i < s1; i += 256) {
        float nm = nmask ? nmask[i] : 1.f;
        float sc = (nm > 0.f) ? expf(attn[i] - m) / sden : 0.f;
        score[i] = sc;
        smax = fmaxf(smax, (nm > 0.f) ? sc : NEGF);
    }
    red[tid] = smax; __syncthreads();
    for (int o = 128; o > 0; o >>= 1) { if (tid < o) red[tid] = fmaxf(red[tid], red[tid + o]); __syncthreads(); }
    smax = red[0]; __syncthreads();
    float thr = fminf(1e-3f, smax - 1e-7f);
    for (int i = s0 + tid; i < s1; i += 256) {
        float nm = nmask ? nmask[i] : 1.f;
        keep[i] = (nm > 0.f && score[i] > thr) ? 1.f : 0.f;
    }
}
__global__ void k_scale(float* __restrict__ x, const float* __restrict__ score,
                        const float* __restrict__ keep) {
    int idx = blockIdx.x * 256 + threadIdx.x;
    int n = idx >> 6;
    x[idx] *= score[n] * keep[n];
}

// ---------------- output head ----------------
__global__ void k_gmax_linear(const float* __restrict__ h, const float* __restrict__ keep2,
                              const int* __restrict__ offs, const float* __restrict__ Wl,
                              const float* __restrict__ bl, float* __restrict__ out) {
    int b = blockIdx.x, tid = threadIdx.x;
    int s0 = offs[b], s1 = offs[b + 1];
    int f = tid & 63, g = tid >> 6;
    float m = NEGF;
    for (int i = s0 + g; i < s1; i += 4)
        if (keep2[i] > 0.f) m = fmaxf(m, h[(size_t)i * 64 + f]);
    __shared__ float red[256];
    red[tid] = m; __syncthreads();
    if (g == 0) {
        m = fmaxf(fmaxf(red[f], red[64 + f]), fmaxf(red[128 + f], red[192 + f]));
        float v = m * Wl[f];
        for (int o = 32; o > 0; o >>= 1) v += __shfl_down(v, o, 64);
        if (f == 0) out[b] = v + bl[0];
    }
}

// ---------------- prefix sum of keep1 (exact int) ----------------
__global__ void k_scan1(const float* __restrict__ keep1, int* __restrict__ prefix,
                        int* __restrict__ bsums) {
    int blk = blockIdx.x, tid = threadIdx.x;
    int base = blk * 1024;
    int vals[4], tsum = 0;
    for (int j = 0; j < 4; ++j) {
        int idx = base + tid * 4 + j;
        int v = (idx < NN && keep1[idx] > 0.f) ? 1 : 0;
        tsum += v; vals[j] = tsum;
    }
    __shared__ int sh[256];
    sh[tid] = tsum; __syncthreads();
    for (int o = 1; o < 256; o <<= 1) {
        int v = (tid >= o) ? sh[tid - o] : 0;
        __syncthreads();
        sh[tid] += v;
        __syncthreads();
    }
    int excl = sh[tid] - tsum;
    for (int j = 0; j < 4; ++j) {
        int idx = base + tid * 4 + j;
        if (idx < NN) prefix[idx] = excl + vals[j];
    }
    if (tid == 255) bsums[blk] = sh[255];
}
__global__ void k_scan2(int* __restrict__ bsums, int nb) {
    int acc = 0;
    for (int i = 0; i < nb; ++i) { int v = bsums[i]; bsums[i] = acc; acc += v; }
}
__global__ void k_scan3(int* __restrict__ prefix, const int* __restrict__ boffs) {
    int idx = blockIdx.x * 256 + threadIdx.x;
    if (idx < NN) prefix[idx] += boffs[idx >> 10];
}

// ---------------- attention KL loss + ratio ----------------
__global__ void k_kl(const float* __restrict__ score2, const float* __restrict__ keep2,
                     const int* __restrict__ prefix, const float* __restrict__ natt,
                     const int* __restrict__ offs, float* __restrict__ out_loss,
                     float* __restrict__ c_total) {
    int b = blockIdx.x, tid = threadIdx.x;
    int s0 = offs[b], s1 = offs[b + 1];
    float s = 0.f, c = 0.f;
    for (int i = s0 + tid; i < s1; i += 256) {
        if (keep2[i] > 0.f) {
            int r1 = prefix[i] - 1;
            r1 = max(0, min(r1, NN - 1));
            float t = natt[r1];
            float logp = logf(score2[i] + 1e-14f);
            float kl = ((t > 0.f) ? t * logf(fmaxf(t, 1e-38f)) : 0.f) - t * logp;
            s += kl; c += 1.f;
        }
    }
    __shared__ float rs[256], rc[256];
    rs[tid] = s; rc[tid] = c; __syncthreads();
    for (int o = 128; o > 0; o >>= 1) {
        if (tid < o) { rs[tid] += rs[tid + o]; rc[tid] += rc[tid + o]; }
        __syncthreads();
    }
    if (tid == 0) {
        out_loss[b] = rs[0] / fmaxf(rc[0], 1.f);
        atomicAdd(c_total, rc[0]);
    }
}
__global__ void k_final(const float* __restrict__ c_total, float* __restrict__ out) {
    out[0] = c_total[0] / (float)NN;
}

extern "C" void kernel_launch(void* const* d_in, const int* in_sizes, int n_in,
                              void* d_out, int out_size, void* d_ws, size_t ws_size,
                              hipStream_t stream) {
    const float* x    = (const float*)d_in[0];
    const int*   src  = (const int*)d_in[1];
    const int*   dst  = (const int*)d_in[2];
    const int*   batch= (const int*)d_in[3];
    const float* natt = (const float*)d_in[4];
    const float* W11 = (const float*)d_in[5],  *b11 = (const float*)d_in[6];
    const float* W12 = (const float*)d_in[7],  *b12 = (const float*)d_in[8];
    const float* gW1 = (const float*)d_in[9],  *gb1 = (const float*)d_in[10];
    const float* W21 = (const float*)d_in[11], *b21 = (const float*)d_in[12];
    const float* W22 = (const float*)d_in[13], *b22 = (const float*)d_in[14];
    const float* gW2 = (const float*)d_in[15], *gb2 = (const float*)d_in[16];
    const float* W31 = (const float*)d_in[17], *b31 = (const float*)d_in[18];
    const float* W32 = (const float*)d_in[19], *b32 = (const float*)d_in[20];
    const float* Wl  = (const float*)d_in[21], *bl  = (const float*)d_in[22];
    float* out = (float*)d_out;

    // workspace layout
    float* agg128 = (float*)d_ws;                 // N*128 (first N*64 reused as agg64)
    float* agg64  = agg128;
    float* tbuf   = agg128 + (size_t)NN * 128;    // N*64
    float* hA     = tbuf + (size_t)NN * 64;       // N*64
    float* hB     = hA + (size_t)NN * 64;         // N*64
    float* hw     = hB + (size_t)NN * 64;         // N
    float* attn   = hw + NN;                      // N
    float* dinv   = attn + NN;                    // N
    float* score1 = dinv + NN;                    // N
    float* score2 = score1 + NN;                  // N
    float* keep1  = score2 + NN;                  // N
    float* keep2  = keep1 + NN;                   // N
    float* degf   = keep2 + NN;                   // N
    int*   prefix = (int*)(degf + NN);            // N
    int*   indeg  = prefix + NN;                  // N
    int*   counts = indeg + NN;                   // B
    int*   offs   = counts + NB;                  // B+1
    int*   bsums  = offs + NB + 1;                // 128
    float* c_total= (float*)(bsums + 128);        // 1

    const int nblk_n   = (NN + 255) / 256;        // node-wise
    const int nblk_n4  = NN / 4;                  // 4 nodes/block
    const int nblk_e   = NE / 256;                // edge-wise
    const int nblk_nf  = NN * 64 / 256;           // node*feat

    // graph offsets
    hipMemsetAsync(counts, 0, NB * sizeof(int), stream);
    k_hist<<<nblk_n, 256, 0, stream>>>(batch, counts);
    k_offs<<<1, 1, 0, stream>>>(counts, offs);

    // ---- GIN1 ----
    hipMemsetAsync(agg128, 0, (size_t)NN * 128 * sizeof(float), stream);
    k_scatter128<<<NE * 32 / 256, 256, 0, stream>>>(x, src, dst, agg128);
    k_mm128<<<nblk_n4, 256, 0, stream>>>(x, agg128, W11, b11, tbuf);
    k_mm64<<<nblk_n4, 256, 0, stream>>>(tbuf, nullptr, W12, b12, hA);

    // ---- SAGPool1 ----
    k_dot_gw<<<nblk_n4, 256, 0, stream>>>(hA, gW1, hw);
    hipMemsetAsync(indeg, 0, NN * sizeof(int), stream);
    k_indeg<<<nblk_e, 256, 0, stream>>>(dst, indeg);
    k_dinv1<<<nblk_n, 256, 0, stream>>>(indeg, dinv);
    hipMemsetAsync(attn, 0, NN * sizeof(float), stream);
    k_attn_edge<<<nblk_e, 256, 0, stream>>>(src, dst, hw, dinv, nullptr, attn);
    k_attn_self<<<nblk_n, 256, 0, stream>>>(attn, hw, dinv, nullptr, gb1);
    k_softmax_pool<<<NB, 256, 0, stream>>>(attn, nullptr, offs, score1, keep1);
    k_scale<<<nblk_nf, 256, 0, stream>>>(hA, score1, keep1);

    // ---- GIN2 ----
    hipMemsetAsync(agg64, 0, (size_t)NN * 64 * sizeof(float), stream);
    k_scatter64<<<NE * 16 / 256, 256, 0, stream>>>(hA, src, dst, keep1, agg64);
    k_mm64<<<nblk_n4, 256, 0, stream>>>(hA, agg64, W21, b21, tbuf);
    k_mm64<<<nblk_n4, 256, 0, stream>>>(tbuf, nullptr, W22, b22, hB);

    // ---- SAGPool2 ----
    k_dot_gw<<<nblk_n4, 256, 0, stream>>>(hB, gW2, hw);
    hipMemsetAsync(degf, 0, NN * sizeof(float), stream);
    k_deg2<<<nblk_e, 256, 0, stream>>>(src, dst, keep1, degf);
    k_dinv2<<<nblk_n, 256, 0, stream>>>(degf, keep1, dinv);
    hipMemsetAsync(attn, 0, NN * sizeof(float), stream);
    k_attn_edge<<<nblk_e, 256, 0, stream>>>(src, dst, hw, dinv, keep1, attn);
    k_attn_self<<<nblk_n, 256, 0, stream>>>(attn, hw, dinv, keep1, gb2);
    k_softmax_pool<<<NB, 256, 0, stream>>>(attn, keep1, offs, score2, keep2);
    k_scale<<<nblk_nf, 256, 0, stream>>>(hB, score2, keep2);

    // ---- GIN3 ----
    hipMemsetAsync(agg64, 0, (size_t)NN * 64 * sizeof(float), stream);
    k_scatter64<<<NE * 16 / 256, 256, 0, stream>>>(hB, src, dst, keep2, agg64);
    k_mm64<<<nblk_n4, 256, 0, stream>>>(hB, agg64, W31, b31, tbuf);
    k_mm64<<<nblk_n4, 256, 0, stream>>>(tbuf, nullptr, W32, b32, hA);

    // ---- head: global max pool + linear ----
    k_gmax_linear<<<NB, 256, 0, stream>>>(hA, keep2, offs, Wl, bl, out);

    // ---- attention KL loss + ratio ----
    k_scan1<<<(NN + 1023) / 1024, 256, 0, stream>>>(keep1, prefix, bsums);
    k_scan2<<<1, 1, 0, stream>>>(bsums, (NN + 1023) / 1024);
    k_scan3<<<nblk_n, 256, 0, stream>>>(prefix, bsums);
    hipMemsetAsync(c_total, 0, sizeof(float), stream);
    k_kl<<<NB, 256, 0, stream>>>(score2, keep2, prefix, natt, offs, out + NB, c_total);
    k_final<<<1, 1, 0, stream>>>(c_total, out + 2 * NB);
}

// Round 3
// 1073.187 us; speedup vs baseline: 5.9808x; 5.9808x over previous
//
#include <hip/hip_runtime.h>
#include <math.h>

#define NN 100000
#define NE 1600000
#define FIN 128
#define HD 64
#define NB 256
#define NEGF (-1e30f)
#define NSCAN_BLK ((NN + 1023) / 1024)

// ---------------- graph offsets via binary search (batch is sorted) ----------------
__global__ void k_offs_bs(const int* __restrict__ batch, int* __restrict__ offs) {
    int g = blockIdx.x * 256 + threadIdx.x;
    if (g > NB) return;
    int lo = 0, hi = NN;
    while (lo < hi) { int mid = (lo + hi) >> 1; if (batch[mid] < g) lo = mid + 1; else hi = mid; }
    offs[g] = lo;
}

// ---------------- CSR (by dst) construction ----------------
__global__ void k_indeg(const int* __restrict__ dst, int* __restrict__ indeg) {
    int e = blockIdx.x * 256 + threadIdx.x;
    if (e < NE) atomicAdd(&indeg[dst[e]], 1);
}
// hierarchical exclusive scan of indeg -> roffs
__global__ void k_iscan_blk(const int* __restrict__ in, int* __restrict__ pref,
                            int* __restrict__ bsums) {
    int blk = blockIdx.x, tid = threadIdx.x;
    int base = blk * 1024;
    int vals[4], tsum = 0;
    for (int j = 0; j < 4; ++j) {
        int idx = base + tid * 4 + j;
        int v = (idx < NN) ? in[idx] : 0;
        vals[j] = tsum; tsum += v;               // exclusive within thread
    }
    __shared__ int sh[256];
    sh[tid] = tsum; __syncthreads();
    for (int o = 1; o < 256; o <<= 1) {
        int v = (tid >= o) ? sh[tid - o] : 0;
        __syncthreads();
        sh[tid] += v;
        __syncthreads();
    }
    int excl = sh[tid] - tsum;
    for (int j = 0; j < 4; ++j) {
        int idx = base + tid * 4 + j;
        if (idx < NN) pref[idx] = excl + vals[j];
    }
    if (tid == 255) bsums[blk] = sh[255];
}
__global__ void k_iscan_mid(int* __restrict__ bsums, int nb, int* __restrict__ roffs) {
    int acc = 0;
    for (int i = 0; i < nb; ++i) { int v = bsums[i]; bsums[i] = acc; acc += v; }
    roffs[NN] = NE;
}
__global__ void k_iscan_add(int* __restrict__ pref, const int* __restrict__ bsums) {
    int idx = blockIdx.x * 256 + threadIdx.x;
    if (idx < NN) pref[idx] += bsums[idx >> 10];
}
__global__ void k_cursor(const int* __restrict__ roffs, int* __restrict__ cursor) {
    int i = blockIdx.x * 256 + threadIdx.x;
    if (i < NN) cursor[i] = roffs[i];
}
__global__ void k_fill(const int* __restrict__ src, const int* __restrict__ dst,
                       int* __restrict__ cursor, int* __restrict__ csrc) {
    int e = blockIdx.x * 256 + threadIdx.x;
    if (e >= NE) return;
    int p = atomicAdd(&cursor[dst[e]], 1);
    csrc[p] = src[e];
}

// ---------------- GIN aggregation (CSR gather) ----------------
// half-wave (32 lanes) per node, float4 per lane -> 128 floats
__global__ void k_gather128(const float* __restrict__ x, const int* __restrict__ roffs,
                            const int* __restrict__ csrc, float* __restrict__ agg) {
    int tid = threadIdx.x;
    int d = blockIdx.x * 8 + (tid >> 5);
    int l = tid & 31;
    const float4* x4 = (const float4*)x;
    float4 acc = make_float4(0.f, 0.f, 0.f, 0.f);
    int e0 = roffs[d], e1 = roffs[d + 1];
    for (int e = e0; e < e1; ++e) {
        int s = csrc[e];
        float4 v = x4[(size_t)s * 32 + l];
        acc.x += v.x; acc.y += v.y; acc.z += v.z; acc.w += v.w;
    }
    ((float4*)agg)[(size_t)d * 32 + l] = acc;
}
// half-wave per node, float2 per lane -> 64 floats; dst-side keep mask
// (src-side mask is implicit: dropped nodes' feature rows are exactly 0)
__global__ void k_gather64(const float* __restrict__ x, const int* __restrict__ roffs,
                           const int* __restrict__ csrc, const float* __restrict__ keep,
                           float* __restrict__ agg) {
    int tid = threadIdx.x;
    int d = blockIdx.x * 8 + (tid >> 5);
    int l = tid & 31;
    const float2* x2 = (const float2*)x;
    float2 acc = make_float2(0.f, 0.f);
    if (keep[d] != 0.f) {
        int e0 = roffs[d], e1 = roffs[d + 1];
        for (int e = e0; e < e1; ++e) {
            int s = csrc[e];
            float2 v = x2[(size_t)s * 32 + l];
            acc.x += v.x; acc.y += v.y;
        }
    }
    ((float2*)agg)[(size_t)d * 32 + l] = acc;
}

// ---------------- MLP layers (relu((a[+agg]) @ W + b)) ----------------
__global__ void k_mm128(const float* __restrict__ x, const float* __restrict__ agg,
                        const float* __restrict__ W, const float* __restrict__ b,
                        float* __restrict__ out) {
    __shared__ float row[4][128];
    int n0 = blockIdx.x * 4, tid = threadIdx.x;
    for (int i = tid; i < 512; i += 256) {
        int r = i >> 7, c = i & 127;
        size_t idx = (size_t)(n0 + r) * 128 + c;
        row[r][c] = x[idx] + agg[idx];
    }
    __syncthreads();
    int r = tid >> 6, f = tid & 63;
    float acc = b[f];
#pragma unroll 8
    for (int k = 0; k < 128; ++k) acc += row[r][k] * W[k * 64 + f];
    out[(size_t)(n0 + r) * 64 + f] = fmaxf(acc, 0.f);
}
__global__ void k_mm64(const float* __restrict__ a, const float* __restrict__ agg,
                       const float* __restrict__ W, const float* __restrict__ b,
                       float* __restrict__ out) {
    __shared__ float row[4][64];
    int n0 = blockIdx.x * 4, tid = threadIdx.x;
    int r = tid >> 6, f = tid & 63;
    size_t idx = (size_t)(n0 + r) * 64 + f;
    float v = a[idx];
    if (agg) v += agg[idx];
    row[r][f] = v;
    __syncthreads();
    float acc = b[f];
#pragma unroll 8
    for (int k = 0; k < 64; ++k) acc += row[r][k] * W[k * 64 + f];
    out[idx] = fmaxf(acc, 0.f);
}

// ---------------- SAG pool pieces ----------------
__global__ void k_dot_gw(const float* __restrict__ h, const float* __restrict__ gW,
                         float* __restrict__ hw) {
    int tid = threadIdx.x;
    int n = blockIdx.x * 4 + (tid >> 6), f = tid & 63;
    float v = h[(size_t)n * 64 + f] * gW[f];
    for (int o = 32; o > 0; o >>= 1) v += __shfl_down(v, o, 64);
    if (f == 0) hw[n] = v;
}
// pool1: dinv = rsqrt(indeg+1); hwd = hw*dinv
__global__ void k_prep1(const int* __restrict__ indeg, const float* __restrict__ hw,
                        float* __restrict__ dinv, float* __restrict__ hwd) {
    int i = blockIdx.x * 256 + threadIdx.x;
    if (i >= NN) return;
    float di = 1.f / sqrtf((float)indeg[i] + 1.0f);
    dinv[i] = di;
    hwd[i] = hw[i] * di;
}
// pool2: deg = keep1[d]*(1 + sum_in keep1[s]); dinv=0 if dropped
__global__ void k_prep2(const int* __restrict__ roffs, const int* __restrict__ csrc,
                        const float* __restrict__ keep1, const float* __restrict__ hw,
                        float* __restrict__ dinv, float* __restrict__ hwd) {
    int i = blockIdx.x * 256 + threadIdx.x;
    if (i >= NN) return;
    float di = 0.f;
    if (keep1[i] != 0.f) {
        float deg = 1.f;
        int e0 = roffs[i], e1 = roffs[i + 1];
        for (int e = e0; e < e1; ++e) deg += keep1[csrc[e]];
        di = 1.f / sqrtf(fmaxf(deg, 1e-12f));
    }
    dinv[i] = di;
    hwd[i] = hw[i] * di;
}
// attn[d] = dinv[d]*sum_in hwd[s] + hw[d]*dinv[d]^2 + gb   (gather, no atomics)
__global__ void k_attn_g(const int* __restrict__ roffs, const int* __restrict__ csrc,
                         const float* __restrict__ hwd, const float* __restrict__ hw,
                         const float* __restrict__ dinv, const float* __restrict__ gb,
                         float* __restrict__ attn) {
    int i = blockIdx.x * 256 + threadIdx.x;
    if (i >= NN) return;
    float sum = 0.f;
    int e0 = roffs[i], e1 = roffs[i + 1];
    for (int e = e0; e < e1; ++e) sum += hwd[csrc[e]];
    float di = dinv[i];
    attn[i] = di * sum + hw[i] * di * di + gb[0];
}
__global__ void k_softmax_pool(const float* __restrict__ attn, const float* __restrict__ nmask,
                               const int* __restrict__ offs, float* __restrict__ score,
                               float* __restrict__ keep) {
    int b = blockIdx.x, tid = threadIdx.x;
    int s0 = offs[b], s1 = offs[b + 1];
    __shared__ float red[256];
    float m = NEGF;
    for (int i = s0 + tid; i < s1; i += 256) {
        float nm = nmask ? nmask[i] : 1.f;
        if (nm > 0.f) m = fmaxf(m, attn[i]);
    }
    red[tid] = m; __syncthreads();
    for (int o = 128; o > 0; o >>= 1) { if (tid < o) red[tid] = fmaxf(red[tid], red[tid + o]); __syncthreads(); }
    m = red[0]; __syncthreads();
    float s = 0.f;
    for (int i = s0 + tid; i < s1; i += 256) {
        float nm = nmask ? nmask[i] : 1.f;
        if (nm > 0.f) s += expf(attn[i] - m);
    }
    red[tid] = s; __syncthreads();
    for (int o = 128; o > 0; o >>= 1) { if (tid < o) red[tid] += red[tid + o]; __syncthreads(); }
    s = red[0]; __syncthreads();
    float sden = fmaxf(s, 1e-30f);
    float smax = NEGF;
    for (int i = s0 + tid; i < s1; i += 256) {
        float nm = nmask ? nmask[i] : 1.f;
        float sc = (nm > 0.f) ? expf(attn[i] - m) / sden : 0.f;
        score[i] = sc;
        smax = fmaxf(smax, (nm > 0.f) ? sc : NEGF);
    }
    red[tid] = smax; __syncthreads();
    for (int o = 128; o > 0; o >>= 1) { if (tid < o) red[tid] = fmaxf(red[tid], red[tid + o]); __syncthreads(); }
    smax = red[0]; __syncthreads();
    float thr = fminf(1e-3f, smax - 1e-7f);
    for (int i = s0 + tid; i < s1; i += 256) {
        float nm = nmask ? nmask[i] : 1.f;
        keep[i] = (nm > 0.f && score[i] > thr) ? 1.f : 0.f;
    }
}
__global__ void k_scale(float* __restrict__ x, const float* __restrict__ score,
                        const float* __restrict__ keep) {
    int idx = blockIdx.x * 256 + threadIdx.x;
    int n = idx >> 6;
    x[idx] *= score[n] * keep[n];
}

// ---------------- output head ----------------
__global__ void k_gmax_linear(const float* __restrict__ h, const float* __restrict__ keep2,
                              const int* __restrict__ offs, const float* __restrict__ Wl,
                              const float* __restrict__ bl, float* __restrict__ out) {
    int b = blockIdx.x, tid = threadIdx.x;
    int s0 = offs[b], s1 = offs[b + 1];
    int f = tid & 63, g = tid >> 6;
    float m = NEGF;
    for (int i = s0 + g; i < s1; i += 4)
        if (keep2[i] > 0.f) m = fmaxf(m, h[(size_t)i * 64 + f]);
    __shared__ float red[256];
    red[tid] = m; __syncthreads();
    if (g == 0) {
        m = fmaxf(fmaxf(red[f], red[64 + f]), fmaxf(red[128 + f], red[192 + f]));
        float v = m * Wl[f];
        for (int o = 32; o > 0; o >>= 1) v += __shfl_down(v, o, 64);
        if (f == 0) out[b] = v + bl[0];
    }
}

// ---------------- prefix sum of keep1 (exact int) ----------------
__global__ void k_scan1(const float* __restrict__ keep1, int* __restrict__ prefix,
                        int* __restrict__ bsums) {
    int blk = blockIdx.x, tid = threadIdx.x;
    int base = blk * 1024;
    int vals[4], tsum = 0;
    for (int j = 0; j < 4; ++j) {
        int idx = base + tid * 4 + j;
        int v = (idx < NN && keep1[idx] > 0.f) ? 1 : 0;
        tsum += v; vals[j] = tsum;
    }
    __shared__ int sh[256];
    sh[tid] = tsum; __syncthreads();
    for (int o = 1; o < 256; o <<= 1) {
        int v = (tid >= o) ? sh[tid - o] : 0;
        __syncthreads();
        sh[tid] += v;
        __syncthreads();
    }
    int excl = sh[tid] - tsum;
    for (int j = 0; j < 4; ++j) {
        int idx = base + tid * 4 + j;
        if (idx < NN) prefix[idx] = excl + vals[j];
    }
    if (tid == 255) bsums[blk] = sh[255];
}
__global__ void k_scan2(int* __restrict__ bsums, int nb) {
    int acc = 0;
    for (int i = 0; i < nb; ++i) { int v = bsums[i]; bsums[i] = acc; acc += v; }
}
__global__ void k_scan3(int* __restrict__ prefix, const int* __restrict__ boffs) {
    int idx = blockIdx.x * 256 + threadIdx.x;
    if (idx < NN) prefix[idx] += boffs[idx >> 10];
}

// ---------------- attention KL loss + ratio ----------------
__global__ void k_kl(const float* __restrict__ score2, const float* __restrict__ keep2,
                     const int* __restrict__ prefix, const float* __restrict__ natt,
                     const int* __restrict__ offs, float* __restrict__ out_loss,
                     float* __restrict__ c_total) {
    int b = blockIdx.x, tid = threadIdx.x;
    int s0 = offs[b], s1 = offs[b + 1];
    float s = 0.f, c = 0.f;
    for (int i = s0 + tid; i < s1; i += 256) {
        if (keep2[i] > 0.f) {
            int r1 = prefix[i] - 1;
            r1 = max(0, min(r1, NN - 1));
            float t = natt[r1];
            float logp = logf(score2[i] + 1e-14f);
            float kl = ((t > 0.f) ? t * logf(fmaxf(t, 1e-38f)) : 0.f) - t * logp;
            s += kl; c += 1.f;
        }
    }
    __shared__ float rs[256], rc[256];
    rs[tid] = s; rc[tid] = c; __syncthreads();
    for (int o = 128; o > 0; o >>= 1) {
        if (tid < o) { rs[tid] += rs[tid + o]; rc[tid] += rc[tid + o]; }
        __syncthreads();
    }
    if (tid == 0) {
        out_loss[b] = rs[0] / fmaxf(rc[0], 1.f);
        atomicAdd(c_total, rc[0]);
    }
}
__global__ void k_final(const float* __restrict__ c_total, float* __restrict__ out) {
    out[0] = c_total[0] / (float)NN;
}

extern "C" void kernel_launch(void* const* d_in, const int* in_sizes, int n_in,
                              void* d_out, int out_size, void* d_ws, size_t ws_size,
                              hipStream_t stream) {
    const float* x    = (const float*)d_in[0];
    const int*   src  = (const int*)d_in[1];
    const int*   dst  = (const int*)d_in[2];
    const int*   batch= (const int*)d_in[3];
    const float* natt = (const float*)d_in[4];
    const float* W11 = (const float*)d_in[5],  *b11 = (const float*)d_in[6];
    const float* W12 = (const float*)d_in[7],  *b12 = (const float*)d_in[8];
    const float* gW1 = (const float*)d_in[9],  *gb1 = (const float*)d_in[10];
    const float* W21 = (const float*)d_in[11], *b21 = (const float*)d_in[12];
    const float* W22 = (const float*)d_in[13], *b22 = (const float*)d_in[14];
    const float* gW2 = (const float*)d_in[15], *gb2 = (const float*)d_in[16];
    const float* W31 = (const float*)d_in[17], *b31 = (const float*)d_in[18];
    const float* W32 = (const float*)d_in[19], *b32 = (const float*)d_in[20];
    const float* Wl  = (const float*)d_in[21], *bl  = (const float*)d_in[22];
    float* out = (float*)d_out;

    // workspace layout
    float* agg128 = (float*)d_ws;                 // N*128 (first N*64 reused as agg64)
    float* agg64  = agg128;
    float* tbuf   = agg128 + (size_t)NN * 128;    // N*64
    float* hA     = tbuf + (size_t)NN * 64;       // N*64
    float* hB     = hA + (size_t)NN * 64;         // N*64
    float* hw     = hB + (size_t)NN * 64;         // N
    float* attn   = hw + NN;                      // N
    float* dinv   = attn + NN;                    // N
    float* hwd    = dinv + NN;                    // N
    float* score1 = hwd + NN;                     // N
    float* score2 = score1 + NN;                  // N
    float* keep1  = score2 + NN;                  // N
    float* keep2  = keep1 + NN;                   // N
    int*   prefix = (int*)(keep2 + NN);           // N
    int*   indeg  = prefix + NN;                  // N
    int*   roffs  = indeg + NN;                   // N+1
    int*   cursor = roffs + NN + 1;               // N
    int*   csrc   = cursor + NN;                  // E
    int*   offs   = csrc + NE;                    // B+1
    int*   bsums  = offs + NB + 1;                // 128
    float* c_total= (float*)(bsums + 128);        // 1

    const int nblk_n   = (NN + 255) / 256;        // node-wise
    const int nblk_n4  = NN / 4;                  // 4 nodes/block
    const int nblk_n8  = NN / 8;                  // 8 nodes/block (half-wave gathers)
    const int nblk_e   = NE / 256;                // edge-wise
    const int nblk_nf  = NN * 64 / 256;           // node*feat

    // graph offsets (batch sorted -> binary search)
    k_offs_bs<<<2, 256, 0, stream>>>(batch, offs);

    // CSR by dst
    hipMemsetAsync(indeg, 0, NN * sizeof(int), stream);
    k_indeg<<<nblk_e, 256, 0, stream>>>(dst, indeg);
    k_iscan_blk<<<NSCAN_BLK, 256, 0, stream>>>(indeg, roffs, bsums);
    k_iscan_mid<<<1, 1, 0, stream>>>(bsums, NSCAN_BLK, roffs);
    k_iscan_add<<<nblk_n, 256, 0, stream>>>(roffs, bsums);
    k_cursor<<<nblk_n, 256, 0, stream>>>(roffs, cursor);
    k_fill<<<nblk_e, 256, 0, stream>>>(src, dst, cursor, csrc);

    // ---- GIN1 ----
    k_gather128<<<nblk_n8, 256, 0, stream>>>(x, roffs, csrc, agg128);
    k_mm128<<<nblk_n4, 256, 0, stream>>>(x, agg128, W11, b11, tbuf);
    k_mm64<<<nblk_n4, 256, 0, stream>>>(tbuf, nullptr, W12, b12, hA);

    // ---- SAGPool1 ----
    k_dot_gw<<<nblk_n4, 256, 0, stream>>>(hA, gW1, hw);
    k_prep1<<<nblk_n, 256, 0, stream>>>(indeg, hw, dinv, hwd);
    k_attn_g<<<nblk_n, 256, 0, stream>>>(roffs, csrc, hwd, hw, dinv, gb1, attn);
    k_softmax_pool<<<NB, 256, 0, stream>>>(attn, nullptr, offs, score1, keep1);
    k_scale<<<nblk_nf, 256, 0, stream>>>(hA, score1, keep1);

    // ---- GIN2 ----
    k_gather64<<<nblk_n8, 256, 0, stream>>>(hA, roffs, csrc, keep1, agg64);
    k_mm64<<<nblk_n4, 256, 0, stream>>>(hA, agg64, W21, b21, tbuf);
    k_mm64<<<nblk_n4, 256, 0, stream>>>(tbuf, nullptr, W22, b22, hB);

    // ---- SAGPool2 ----
    k_dot_gw<<<nblk_n4, 256, 0, stream>>>(hB, gW2, hw);
    k_prep2<<<nblk_n, 256, 0, stream>>>(roffs, csrc, keep1, hw, dinv, hwd);
    k_attn_g<<<nblk_n, 256, 0, stream>>>(roffs, csrc, hwd, hw, dinv, gb2, attn);
    k_softmax_pool<<<NB, 256, 0, stream>>>(attn, keep1, offs, score2, keep2);
    k_scale<<<nblk_nf, 256, 0, stream>>>(hB, score2, keep2);

    // ---- GIN3 ----
    k_gather64<<<nblk_n8, 256, 0, stream>>>(hB, roffs, csrc, keep2, agg64);
    k_mm64<<<nblk_n4, 256, 0, stream>>>(hB, agg64, W31, b31, tbuf);
    k_mm64<<<nblk_n4, 256, 0, stream>>>(tbuf, nullptr, W32, b32, hA);

    // ---- head: global max pool + linear ----
    k_gmax_linear<<<NB, 256, 0, stream>>>(hA, keep2, offs, Wl, bl, out);

    // ---- attention KL loss + ratio ----
    k_scan1<<<NSCAN_BLK, 256, 0, stream>>>(keep1, prefix, bsums);
    k_scan2<<<1, 1, 0, stream>>>(bsums, NSCAN_BLK);
    k_scan3<<<nblk_n, 256, 0, stream>>>(prefix, bsums);
    hipMemsetAsync(c_total, 0, sizeof(float), stream);
    k_kl<<<NB, 256, 0, stream>>>(score2, keep2, prefix, natt, offs, out + NB, c_total);
    k_final<<<1, 1, 0, stream>>>(c_total, out + 2 * NB);
}

// Round 6
// 961.021 us; speedup vs baseline: 6.6788x; 1.1167x over previous
//
#include <hip/hip_runtime.h>
#include <math.h>

#define NN 100000
#define NE 1600000
#define NB 256
#define NEGF (-1e30f)
#define NSCAN_BLK ((NN + 1023) / 1024)

// ---------------- graph offsets via binary search (batch is sorted) ----------------
__global__ void k_offs_bs(const int* __restrict__ batch, int* __restrict__ offs) {
    int g = blockIdx.x * 256 + threadIdx.x;
    if (g > NB) return;
    int lo = 0, hi = NN;
    while (lo < hi) { int mid = (lo + hi) >> 1; if (batch[mid] < g) lo = mid + 1; else hi = mid; }
    offs[g] = lo;
}

// ---------------- CSR (by dst) construction ----------------
__global__ void k_indeg(const int* __restrict__ dst, int* __restrict__ indeg) {
    int e = blockIdx.x * 256 + threadIdx.x;
    if (e < NE) atomicAdd(&indeg[dst[e]], 1);
}
__global__ void k_iscan_blk(const int* __restrict__ in, int* __restrict__ pref,
                            int* __restrict__ bsums) {
    int blk = blockIdx.x, tid = threadIdx.x;
    int base = blk * 1024;
    int vals[4], tsum = 0;
    for (int j = 0; j < 4; ++j) {
        int idx = base + tid * 4 + j;
        int v = (idx < NN) ? in[idx] : 0;
        vals[j] = tsum; tsum += v;               // exclusive within thread
    }
    __shared__ int sh[256];
    sh[tid] = tsum; __syncthreads();
    for (int o = 1; o < 256; o <<= 1) {
        int v = (tid >= o) ? sh[tid - o] : 0;
        __syncthreads();
        sh[tid] += v;
        __syncthreads();
    }
    int excl = sh[tid] - tsum;
    for (int j = 0; j < 4; ++j) {
        int idx = base + tid * 4 + j;
        if (idx < NN) pref[idx] = excl + vals[j];
    }
    if (tid == 255) bsums[blk] = sh[255];
}
__global__ void k_iscan_mid(int* __restrict__ bsums, int nb, int* __restrict__ roffs) {
    int acc = 0;
    for (int i = 0; i < nb; ++i) { int v = bsums[i]; bsums[i] = acc; acc += v; }
    roffs[NN] = NE;
}
// adds block offsets AND initializes the fill cursor (fused)
__global__ void k_iscan_add(int* __restrict__ pref, const int* __restrict__ bsums,
                            int* __restrict__ cursor) {
    int idx = blockIdx.x * 256 + threadIdx.x;
    if (idx < NN) {
        int v = pref[idx] + bsums[idx >> 10];
        pref[idx] = v;
        cursor[idx] = v;
    }
}
__global__ void k_fill(const int* __restrict__ src, const int* __restrict__ dst,
                       int* __restrict__ cursor, int* __restrict__ csrc) {
    int e = blockIdx.x * 256 + threadIdx.x;
    if (e >= NE) return;
    int p = atomicAdd(&cursor[dst[e]], 1);
    csrc[p] = src[e];
}

// ---------------- fused GIN1: gather(128) + self + MLP(128->64->64) + score-dot ----------------
// one wave per node; lane l covers features 2l,2l+1 during gather, feature l in MLP.
__global__ void k_gin1(const float* __restrict__ x, const int* __restrict__ roffs,
                       const int* __restrict__ csrc, const int* __restrict__ indeg,
                       const float* __restrict__ W1, const float* __restrict__ b1,
                       const float* __restrict__ W2, const float* __restrict__ b2,
                       const float* __restrict__ gW,
                       float* __restrict__ hOut, float* __restrict__ hwd,
                       float* __restrict__ dinv) {
    __shared__ float rowA[4][128];
    __shared__ float rowB[4][64];
    int tid = threadIdx.x;
    int w = tid >> 6, l = tid & 63;
    int d = blockIdx.x * 4 + w;
    const float2* x2 = (const float2*)x;
    float2 acc = x2[(size_t)d * 64 + l];            // self term
    int e0 = roffs[d], e1 = roffs[d + 1];
    int e = e0;
    for (; e + 1 < e1; e += 2) {
        int s0 = csrc[e], s1 = csrc[e + 1];
        float2 v0 = x2[(size_t)s0 * 64 + l];
        float2 v1 = x2[(size_t)s1 * 64 + l];
        acc.x += v0.x + v1.x; acc.y += v0.y + v1.y;
    }
    if (e < e1) {
        float2 v0 = x2[(size_t)csrc[e] * 64 + l];
        acc.x += v0.x; acc.y += v0.y;
    }
    rowA[w][2 * l] = acc.x; rowA[w][2 * l + 1] = acc.y;
    __builtin_amdgcn_wave_barrier();                // wave-local LDS: no block barrier needed
    float a1 = b1[l];
#pragma unroll 8
    for (int k = 0; k < 128; ++k) a1 += rowA[w][k] * W1[k * 64 + l];
    a1 = fmaxf(a1, 0.f);
    rowB[w][l] = a1;
    __builtin_amdgcn_wave_barrier();
    float a2 = b2[l];
#pragma unroll 8
    for (int k = 0; k < 64; ++k) a2 += rowB[w][k] * W2[k * 64 + l];
    a2 = fmaxf(a2, 0.f);                            // outer relu
    hOut[(size_t)d * 64 + l] = a2;
    float v = a2 * gW[l];
    for (int o = 32; o > 0; o >>= 1) v += __shfl_down(v, o, 64);
    if (l == 0) {
        float di = 1.f / sqrtf((float)indeg[d] + 1.f);
        dinv[d] = di;
        hwd[d] = v * di;
    }
}

// ---------------- fused GIN2/GIN3: gather(64, scaled) + self + MLP(64->64->64) ----------------
// scale (score*keep) is folded into the reads; pool2 degree count folded into the gather.
__global__ void k_gin64(const float* __restrict__ h, const int* __restrict__ roffs,
                        const int* __restrict__ csrc, const float* __restrict__ sk,
                        const float* __restrict__ keep,
                        const float* __restrict__ W1, const float* __restrict__ b1,
                        const float* __restrict__ W2, const float* __restrict__ b2,
                        const float* __restrict__ gW,   // null for GIN3
                        float* __restrict__ hOut, float* __restrict__ hwd,
                        float* __restrict__ dinv) {
    __shared__ float rowA[4][64];
    __shared__ float rowB[4][64];
    int tid = threadIdx.x;
    int w = tid >> 6, l = tid & 63;
    int d = blockIdx.x * 4 + w;
    float kd = keep[d];
    float v = h[(size_t)d * 64 + l] * sk[d];        // self (scaled)
    int cnt = 0;
    if (kd != 0.f) {                                 // dst-side edge mask (wave-uniform)
        int e0 = roffs[d], e1 = roffs[d + 1];
        int e = e0;
        for (; e + 1 < e1; e += 2) {
            int s0 = csrc[e], s1 = csrc[e + 1];
            float k0 = sk[s0], k1 = sk[s1];
            v += h[(size_t)s0 * 64 + l] * k0 + h[(size_t)s1 * 64 + l] * k1;
            cnt += (k0 > 0.f) + (k1 > 0.f);
        }
        if (e < e1) {
            int s0 = csrc[e];
            float k0 = sk[s0];
            v += h[(size_t)s0 * 64 + l] * k0;
            cnt += (k0 > 0.f);
        }
    }
    rowA[w][l] = v;
    __builtin_amdgcn_wave_barrier();
    float a1 = b1[l];
#pragma unroll 8
    for (int k = 0; k < 64; ++k) a1 += rowA[w][k] * W1[k * 64 + l];
    a1 = fmaxf(a1, 0.f);
    rowB[w][l] = a1;
    __builtin_amdgcn_wave_barrier();
    float a2 = b2[l];
#pragma unroll 8
    for (int k = 0; k < 64; ++k) a2 += rowB[w][k] * W2[k * 64 + l];
    a2 = fmaxf(a2, 0.f);
    hOut[(size_t)d * 64 + l] = a2;
    if (gW) {
        float t = a2 * gW[l];
        for (int o = 32; o > 0; o >>= 1) t += __shfl_down(t, o, 64);
        if (l == 0) {
            float di = (kd != 0.f) ? 1.f / sqrtf((float)(cnt + 1)) : 0.f;
            dinv[d] = di;
            hwd[d] = t * di;
        }
    }
}

// ---------------- attention gather: attn[i] = dinv[i]*(sum_nbr hwd + hwd[i]) + gb ----------------
__global__ void k_attn(const int* __restrict__ roffs, const int* __restrict__ csrc,
                       const float* __restrict__ hwd, const float* __restrict__ dinv,
                       const float* __restrict__ gb, float* __restrict__ attn) {
    int i = blockIdx.x * 256 + threadIdx.x;
    if (i >= NN) return;
    float sum = hwd[i];
    int e0 = roffs[i], e1 = roffs[i + 1];
    for (int e = e0; e < e1; ++e) sum += hwd[csrc[e]];
    attn[i] = dinv[i] * sum + gb[0];
}

// ---------------- per-graph softmax + threshold; also emits sk = score*keep ----------------
__global__ void k_softmax_pool(const float* __restrict__ attn, const float* __restrict__ nmask,
                               const int* __restrict__ offs, float* __restrict__ score,
                               float* __restrict__ keep, float* __restrict__ sk) {
    int b = blockIdx.x, tid = threadIdx.x;
    int s0 = offs[b], s1 = offs[b + 1];
    __shared__ float red[256];
    float m = NEGF;
    for (int i = s0 + tid; i < s1; i += 256) {
        float nm = nmask ? nmask[i] : 1.f;
        if (nm > 0.f) m = fmaxf(m, attn[i]);
    }
    red[tid] = m; __syncthreads();
    for (int o = 128; o > 0; o >>= 1) { if (tid < o) red[tid] = fmaxf(red[tid], red[tid + o]); __syncthreads(); }
    m = red[0]; __syncthreads();
    float s = 0.f;
    for (int i = s0 + tid; i < s1; i += 256) {
        float nm = nmask ? nmask[i] : 1.f;
        if (nm > 0.f) s += expf(attn[i] - m);
    }
    red[tid] = s; __syncthreads();
    for (int o = 128; o > 0; o >>= 1) { if (tid < o) red[tid] += red[tid + o]; __syncthreads(); }
    s = red[0]; __syncthreads();
    float sden = fmaxf(s, 1e-30f);
    float smax = NEGF;
    for (int i = s0 + tid; i < s1; i += 256) {
        float nm = nmask ? nmask[i] : 1.f;
        float sc = (nm > 0.f) ? expf(attn[i] - m) / sden : 0.f;
        score[i] = sc;
        smax = fmaxf(smax, (nm > 0.f) ? sc : NEGF);
    }
    red[tid] = smax; __syncthreads();
    for (int o = 128; o > 0; o >>= 1) { if (tid < o) red[tid] = fmaxf(red[tid], red[tid + o]); __syncthreads(); }
    smax = red[0]; __syncthreads();
    float thr = fminf(1e-3f, smax - 1e-7f);
    for (int i = s0 + tid; i < s1; i += 256) {
        float nm = nmask ? nmask[i] : 1.f;
        float sc = score[i];
        float kp = (nm > 0.f && sc > thr) ? 1.f : 0.f;
        keep[i] = kp;
        sk[i] = sc * kp;
    }
}

// ---------------- output head ----------------
__global__ void k_gmax_linear(const float* __restrict__ h, const float* __restrict__ keep2,
                              const int* __restrict__ offs, const float* __restrict__ Wl,
                              const float* __restrict__ bl, float* __restrict__ out) {
    int b = blockIdx.x, tid = threadIdx.x;
    int s0 = offs[b], s1 = offs[b + 1];
    int f = tid & 63, g = tid >> 6;
    float m = NEGF;
    for (int i = s0 + g; i < s1; i += 4)
        if (keep2[i] > 0.f) m = fmaxf(m, h[(size_t)i * 64 + f]);
    __shared__ float red[256];
    red[tid] = m; __syncthreads();
    if (g == 0) {
        m = fmaxf(fmaxf(red[f], red[64 + f]), fmaxf(red[128 + f], red[192 + f]));
        float v = m * Wl[f];
        for (int o = 32; o > 0; o >>= 1) v += __shfl_down(v, o, 64);
        if (f == 0) out[b] = v + bl[0];
    }
}

// ---------------- prefix sum of keep1 (exact int) ----------------
__global__ void k_scan1(const float* __restrict__ keep1, int* __restrict__ prefix,
                        int* __restrict__ bsums) {
    int blk = blockIdx.x, tid = threadIdx.x;
    int base = blk * 1024;
    int vals[4], tsum = 0;
    for (int j = 0; j < 4; ++j) {
        int idx = base + tid * 4 + j;
        int v = (idx < NN && keep1[idx] > 0.f) ? 1 : 0;
        tsum += v; vals[j] = tsum;
    }
    __shared__ int sh[256];
    sh[tid] = tsum; __syncthreads();
    for (int o = 1; o < 256; o <<= 1) {
        int v = (tid >= o) ? sh[tid - o] : 0;
        __syncthreads();
        sh[tid] += v;
        __syncthreads();
    }
    int excl = sh[tid] - tsum;
    for (int j = 0; j < 4; ++j) {
        int idx = base + tid * 4 + j;
        if (idx < NN) prefix[idx] = excl + vals[j];
    }
    if (tid == 255) bsums[blk] = sh[255];
}
__global__ void k_scan2(int* __restrict__ bsums, int nb) {
    int acc = 0;
    for (int i = 0; i < nb; ++i) { int v = bsums[i]; bsums[i] = acc; acc += v; }
}
__global__ void k_scan3(int* __restrict__ prefix, const int* __restrict__ boffs) {
    int idx = blockIdx.x * 256 + threadIdx.x;
    if (idx < NN) prefix[idx] += boffs[idx >> 10];
}

// ---------------- attention KL loss + ratio ----------------
__global__ void k_kl(const float* __restrict__ score2, const float* __restrict__ keep2,
                     const int* __restrict__ prefix, const float* __restrict__ natt,
                     const int* __restrict__ offs, float* __restrict__ out_loss,
                     float* __restrict__ c_total) {
    int b = blockIdx.x, tid = threadIdx.x;
    int s0 = offs[b], s1 = offs[b + 1];
    float s = 0.f, c = 0.f;
    for (int i = s0 + tid; i < s1; i += 256) {
        if (keep2[i] > 0.f) {
            int r1 = prefix[i] - 1;
            r1 = max(0, min(r1, NN - 1));
            float t = natt[r1];
            float logp = logf(score2[i] + 1e-14f);
            float kl = ((t > 0.f) ? t * logf(fmaxf(t, 1e-38f)) : 0.f) - t * logp;
            s += kl; c += 1.f;
        }
    }
    __shared__ float rs[256], rc[256];
    rs[tid] = s; rc[tid] = c; __syncthreads();
    for (int o = 128; o > 0; o >>= 1) {
        if (tid < o) { rs[tid] += rs[tid + o]; rc[tid] += rc[tid + o]; }
        __syncthreads();
    }
    if (tid == 0) {
        out_loss[b] = rs[0] / fmaxf(rc[0], 1.f);
        atomicAdd(c_total, rc[0]);
    }
}
__global__ void k_final(const float* __restrict__ c_total, float* __restrict__ out) {
    out[0] = c_total[0] / (float)NN;
}

extern "C" void kernel_launch(void* const* d_in, const int* in_sizes, int n_in,
                              void* d_out, int out_size, void* d_ws, size_t ws_size,
                              hipStream_t stream) {
    const float* x    = (const float*)d_in[0];
    const int*   src  = (const int*)d_in[1];
    const int*   dst  = (const int*)d_in[2];
    const int*   batch= (const int*)d_in[3];
    const float* natt = (const float*)d_in[4];
    const float* W11 = (const float*)d_in[5],  *b11 = (const float*)d_in[6];
    const float* W12 = (const float*)d_in[7],  *b12 = (const float*)d_in[8];
    const float* gW1 = (const float*)d_in[9],  *gb1 = (const float*)d_in[10];
    const float* W21 = (const float*)d_in[11], *b21 = (const float*)d_in[12];
    const float* W22 = (const float*)d_in[13], *b22 = (const float*)d_in[14];
    const float* gW2 = (const float*)d_in[15], *gb2 = (const float*)d_in[16];
    const float* W31 = (const float*)d_in[17], *b31 = (const float*)d_in[18];
    const float* W32 = (const float*)d_in[19], *b32 = (const float*)d_in[20];
    const float* Wl  = (const float*)d_in[21], *bl  = (const float*)d_in[22];
    float* out = (float*)d_out;

    // workspace layout
    float* hA     = (float*)d_ws;                 // N*64
    float* hB     = hA + (size_t)NN * 64;         // N*64
    float* h3     = hB + (size_t)NN * 64;         // N*64
    float* hwd    = h3 + (size_t)NN * 64;         // N
    float* dinv   = hwd + NN;                     // N
    float* attn   = dinv + NN;                    // N
    float* score1 = attn + NN;                    // N
    float* keep1  = score1 + NN;                  // N
    float* sk1    = keep1 + NN;                   // N
    float* score2 = sk1 + NN;                     // N
    float* keep2  = score2 + NN;                  // N
    float* sk2    = keep2 + NN;                   // N
    int*   prefix = (int*)(sk2 + NN);             // N
    int*   indeg  = prefix + NN;                  // N
    int*   roffs  = indeg + NN;                   // N+1
    int*   cursor = roffs + NN + 1;               // N
    int*   csrc   = cursor + NN;                  // E
    int*   offs   = csrc + NE;                    // B+1
    int*   bsums  = offs + NB + 1;                // 128
    float* c_total= (float*)(bsums + 128);        // 1

    const int nblk_n  = (NN + 255) / 256;
    const int nblk_n4 = NN / 4;
    const int nblk_e  = NE / 256;

    // graph offsets (batch sorted -> binary search)
    k_offs_bs<<<2, 256, 0, stream>>>(batch, offs);

    // CSR by dst
    hipMemsetAsync(indeg, 0, NN * sizeof(int), stream);
    k_indeg<<<nblk_e, 256, 0, stream>>>(dst, indeg);
    k_iscan_blk<<<NSCAN_BLK, 256, 0, stream>>>(indeg, roffs, bsums);
    k_iscan_mid<<<1, 1, 0, stream>>>(bsums, NSCAN_BLK, roffs);
    k_iscan_add<<<nblk_n, 256, 0, stream>>>(roffs, bsums, cursor);
    k_fill<<<nblk_e, 256, 0, stream>>>(src, dst, cursor, csrc);

    // ---- GIN1 (fused) + pool1 attention prep ----
    k_gin1<<<nblk_n4, 256, 0, stream>>>(x, roffs, csrc, indeg,
                                        W11, b11, W12, b12, gW1, hA, hwd, dinv);
    k_attn<<<nblk_n, 256, 0, stream>>>(roffs, csrc, hwd, dinv, gb1, attn);
    k_softmax_pool<<<NB, 256, 0, stream>>>(attn, nullptr, offs, score1, keep1, sk1);

    // ---- GIN2 (fused, scale folded) + pool2 attention prep ----
    k_gin64<<<nblk_n4, 256, 0, stream>>>(hA, roffs, csrc, sk1, keep1,
                                         W21, b21, W22, b22, gW2, hB, hwd, dinv);
    k_attn<<<nblk_n, 256, 0, stream>>>(roffs, csrc, hwd, dinv, gb2, attn);
    k_softmax_pool<<<NB, 256, 0, stream>>>(attn, keep1, offs, score2, keep2, sk2);

    // ---- GIN3 (fused, scale folded) ----
    k_gin64<<<nblk_n4, 256, 0, stream>>>(hB, roffs, csrc, sk2, keep2,
                                         W31, b31, W32, b32, nullptr, h3, hwd, dinv);

    // ---- head: global max pool + linear ----
    k_gmax_linear<<<NB, 256, 0, stream>>>(h3, keep2, offs, Wl, bl, out);

    // ---- attention KL loss + ratio ----
    k_scan1<<<NSCAN_BLK, 256, 0, stream>>>(keep1, prefix, bsums);
    k_scan2<<<1, 1, 0, stream>>>(bsums, NSCAN_BLK);
    k_scan3<<<nblk_n, 256, 0, stream>>>(prefix, bsums);
    hipMemsetAsync(c_total, 0, sizeof(float), stream);
    k_kl<<<NB, 256, 0, stream>>>(score2, keep2, prefix, natt, offs, out + NB, c_total);
    k_final<<<1, 1, 0, stream>>>(c_total, out + 2 * NB);
}

// Round 7
// 912.505 us; speedup vs baseline: 7.0339x; 1.0532x over previous
//
#include <hip/hip_runtime.h>
#include <math.h>

#define NN 100000
#define NE 1600000
#define NB 256
#define NEGF (-1e30f)
#define NSCAN_BLK ((NN + 1023) / 1024)

// ---------------- graph offsets via binary search (batch is sorted) ----------------
__global__ void k_offs_bs(const int* __restrict__ batch, int* __restrict__ offs) {
    int g = blockIdx.x * 256 + threadIdx.x;
    if (g > NB) return;
    int lo = 0, hi = NN;
    while (lo < hi) { int mid = (lo + hi) >> 1; if (batch[mid] < g) lo = mid + 1; else hi = mid; }
    offs[g] = lo;
}

// ---------------- CSR (by dst) construction ----------------
__global__ void k_indeg(const int* __restrict__ dst, int* __restrict__ indeg) {
    int e = blockIdx.x * 256 + threadIdx.x;
    if (e < NE) atomicAdd(&indeg[dst[e]], 1);
}
__global__ void k_iscan_blk(const int* __restrict__ in, int* __restrict__ pref,
                            int* __restrict__ bsums) {
    int blk = blockIdx.x, tid = threadIdx.x;
    int base = blk * 1024;
    int vals[4], tsum = 0;
    for (int j = 0; j < 4; ++j) {
        int idx = base + tid * 4 + j;
        int v = (idx < NN) ? in[idx] : 0;
        vals[j] = tsum; tsum += v;               // exclusive within thread
    }
    __shared__ int sh[256];
    sh[tid] = tsum; __syncthreads();
    for (int o = 1; o < 256; o <<= 1) {
        int v = (tid >= o) ? sh[tid - o] : 0;
        __syncthreads();
        sh[tid] += v;
        __syncthreads();
    }
    int excl = sh[tid] - tsum;
    for (int j = 0; j < 4; ++j) {
        int idx = base + tid * 4 + j;
        if (idx < NN) pref[idx] = excl + vals[j];
    }
    if (tid == 255) bsums[blk] = sh[255];
}
__global__ void k_iscan_mid(int* __restrict__ bsums, int nb, int* __restrict__ roffs) {
    int acc = 0;
    for (int i = 0; i < nb; ++i) { int v = bsums[i]; bsums[i] = acc; acc += v; }
    roffs[NN] = NE;
}
// adds block offsets AND initializes the fill cursor (fused)
__global__ void k_iscan_add(int* __restrict__ pref, const int* __restrict__ bsums,
                            int* __restrict__ cursor) {
    int idx = blockIdx.x * 256 + threadIdx.x;
    if (idx < NN) {
        int v = pref[idx] + bsums[idx >> 10];
        pref[idx] = v;
        cursor[idx] = v;
    }
}
__global__ void k_fill(const int* __restrict__ src, const int* __restrict__ dst,
                       int* __restrict__ cursor, int* __restrict__ csrc) {
    int e = blockIdx.x * 256 + threadIdx.x;
    if (e >= NE) return;
    int p = atomicAdd(&cursor[dst[e]], 1);
    csrc[p] = src[e];
}

// ---------------- pre-GEMM: y = x @ W (128->64) ----------------
__global__ void k_pre1(const float* __restrict__ x, const float* __restrict__ W,
                       float* __restrict__ y) {
    __shared__ float row[4][128];
    int tid = threadIdx.x;
    int w = tid >> 6, l = tid & 63;
    int d = blockIdx.x * 4 + w;
    const float2* x2 = (const float2*)x;
    float2 v = x2[(size_t)d * 64 + l];
    row[w][2 * l] = v.x; row[w][2 * l + 1] = v.y;
    __builtin_amdgcn_wave_barrier();
    float a = 0.f;
#pragma unroll 8
    for (int k = 0; k < 128; ++k) a += row[w][k] * W[k * 64 + l];
    y[(size_t)d * 64 + l] = a;
}

// ---------------- pre-GEMM: y = (h * sk) @ W (64->64); zero row if sk==0 ----------------
__global__ void k_pre23(const float* __restrict__ h, const float* __restrict__ sk,
                        const float* __restrict__ W, float* __restrict__ y) {
    __shared__ float row[4][64];
    int tid = threadIdx.x;
    int w = tid >> 6, l = tid & 63;
    int d = blockIdx.x * 4 + w;
    float sc = sk[d];
    if (sc == 0.f) {                 // wave-uniform: dropped node -> zero row
        y[(size_t)d * 64 + l] = 0.f;
        return;
    }
    row[w][l] = h[(size_t)d * 64 + l] * sc;
    __builtin_amdgcn_wave_barrier();
    float a = 0.f;
#pragma unroll 8
    for (int k = 0; k < 64; ++k) a += row[w][k] * W[k * 64 + l];
    y[(size_t)d * 64 + l] = a;
}

// ---------------- pure CSR gather of transformed rows: z[d] = y[d] + [gate] sum y[s] ----------
// half-wave (32 lanes) per node, float2 per lane (256 B rows). Optional kept-neighbor count.
__global__ void k_gather_y(const float* __restrict__ y, const int* __restrict__ roffs,
                           const int* __restrict__ csrc, const float* __restrict__ keepd,
                           const float* __restrict__ sk, float* __restrict__ z,
                           int* __restrict__ cnt) {
    int tid = threadIdx.x;
    int d = blockIdx.x * 8 + (tid >> 5);
    int l = tid & 31;
    const float2* y2 = (const float2*)y;
    float2 acc = y2[(size_t)d * 32 + l];            // self term
    int c = 0;
    if (!keepd || keepd[d] != 0.f) {                // dst-side gate (wave-uniform)
        int e0 = roffs[d], e1 = roffs[d + 1];
        int e = e0;
        for (; e + 1 < e1; e += 2) {
            int s0 = csrc[e], s1 = csrc[e + 1];
            float2 v0 = y2[(size_t)s0 * 32 + l];
            float2 v1 = y2[(size_t)s1 * 32 + l];
            acc.x += v0.x + v1.x; acc.y += v0.y + v1.y;
            if (sk) c += (sk[s0] > 0.f) + (sk[s1] > 0.f);
        }
        if (e < e1) {
            int s0 = csrc[e];
            float2 v0 = y2[(size_t)s0 * 32 + l];
            acc.x += v0.x; acc.y += v0.y;
            if (sk) c += (sk[s0] > 0.f);
        }
    }
    ((float2*)z)[(size_t)d * 32 + l] = acc;
    if (cnt && l == 0) cnt[d] = c;
}

// ---------------- post: h = relu(relu(z+b1)@W2 + b2) [+ score-dot + dinv epilogue] --------
// mode 1: dinv from indeg (pool1). mode 2: dinv from cnt & keep (pool2). mode 3: no epilogue.
__global__ void k_post(const float* __restrict__ z, const float* __restrict__ b1,
                       const float* __restrict__ W2, const float* __restrict__ b2,
                       const float* __restrict__ gW, const int* __restrict__ indeg,
                       const int* __restrict__ cnt, const float* __restrict__ keep,
                       float* __restrict__ hOut, float* __restrict__ hwd,
                       float* __restrict__ dinv, int mode) {
    __shared__ float row[4][64];
    int tid = threadIdx.x;
    int w = tid >> 6, l = tid & 63;
    int d = blockIdx.x * 4 + w;
    float r = fmaxf(z[(size_t)d * 64 + l] + b1[l], 0.f);
    row[w][l] = r;
    __builtin_amdgcn_wave_barrier();
    float a = b2[l];
#pragma unroll 8
    for (int k = 0; k < 64; ++k) a += row[w][k] * W2[k * 64 + l];
    a = fmaxf(a, 0.f);
    hOut[(size_t)d * 64 + l] = a;
    if (mode < 3) {
        float t = a * gW[l];
        for (int o = 32; o > 0; o >>= 1) t += __shfl_down(t, o, 64);
        if (l == 0) {
            float di;
            if (mode == 1) di = 1.f / sqrtf((float)indeg[d] + 1.f);
            else di = (keep[d] != 0.f) ? 1.f / sqrtf((float)cnt[d] + 1.f) : 0.f;
            dinv[d] = di;
            hwd[d] = t * di;
        }
    }
}

// ---------------- attention gather: attn[i] = dinv[i]*(sum_nbr hwd + hwd[i]) + gb ----------------
__global__ void k_attn(const int* __restrict__ roffs, const int* __restrict__ csrc,
                       const float* __restrict__ hwd, const float* __restrict__ dinv,
                       const float* __restrict__ gb, float* __restrict__ attn) {
    int i = blockIdx.x * 256 + threadIdx.x;
    if (i >= NN) return;
    float sum = hwd[i];
    int e0 = roffs[i], e1 = roffs[i + 1];
    for (int e = e0; e < e1; ++e) sum += hwd[csrc[e]];
    attn[i] = dinv[i] * sum + gb[0];
}

// ---------------- per-graph softmax + threshold; also emits sk = score*keep ----------------
__global__ void k_softmax_pool(const float* __restrict__ attn, const float* __restrict__ nmask,
                               const int* __restrict__ offs, float* __restrict__ score,
                               float* __restrict__ keep, float* __restrict__ sk) {
    int b = blockIdx.x, tid = threadIdx.x;
    int s0 = offs[b], s1 = offs[b + 1];
    __shared__ float red[256];
    float m = NEGF;
    for (int i = s0 + tid; i < s1; i += 256) {
        float nm = nmask ? nmask[i] : 1.f;
        if (nm > 0.f) m = fmaxf(m, attn[i]);
    }
    red[tid] = m; __syncthreads();
    for (int o = 128; o > 0; o >>= 1) { if (tid < o) red[tid] = fmaxf(red[tid], red[tid + o]); __syncthreads(); }
    m = red[0]; __syncthreads();
    float s = 0.f;
    for (int i = s0 + tid; i < s1; i += 256) {
        float nm = nmask ? nmask[i] : 1.f;
        if (nm > 0.f) s += expf(attn[i] - m);
    }
    red[tid] = s; __syncthreads();
    for (int o = 128; o > 0; o >>= 1) { if (tid < o) red[tid] += red[tid + o]; __syncthreads(); }
    s = red[0]; __syncthreads();
    float sden = fmaxf(s, 1e-30f);
    float smax = NEGF;
    for (int i = s0 + tid; i < s1; i += 256) {
        float nm = nmask ? nmask[i] : 1.f;
        float sc = (nm > 0.f) ? expf(attn[i] - m) / sden : 0.f;
        score[i] = sc;
        smax = fmaxf(smax, (nm > 0.f) ? sc : NEGF);
    }
    red[tid] = smax; __syncthreads();
    for (int o = 128; o > 0; o >>= 1) { if (tid < o) red[tid] = fmaxf(red[tid], red[tid + o]); __syncthreads(); }
    smax = red[0]; __syncthreads();
    float thr = fminf(1e-3f, smax - 1e-7f);
    for (int i = s0 + tid; i < s1; i += 256) {
        float nm = nmask ? nmask[i] : 1.f;
        float sc = score[i];
        float kp = (nm > 0.f && sc > thr) ? 1.f : 0.f;
        keep[i] = kp;
        sk[i] = sc * kp;
    }
}

// ---------------- output head ----------------
__global__ void k_gmax_linear(const float* __restrict__ h, const float* __restrict__ keep2,
                              const int* __restrict__ offs, const float* __restrict__ Wl,
                              const float* __restrict__ bl, float* __restrict__ out) {
    int b = blockIdx.x, tid = threadIdx.x;
    int s0 = offs[b], s1 = offs[b + 1];
    int f = tid & 63, g = tid >> 6;
    float m = NEGF;
    for (int i = s0 + g; i < s1; i += 4)
        if (keep2[i] > 0.f) m = fmaxf(m, h[(size_t)i * 64 + f]);
    __shared__ float red[256];
    red[tid] = m; __syncthreads();
    if (g == 0) {
        m = fmaxf(fmaxf(red[f], red[64 + f]), fmaxf(red[128 + f], red[192 + f]));
        float v = m * Wl[f];
        for (int o = 32; o > 0; o >>= 1) v += __shfl_down(v, o, 64);
        if (f == 0) out[b] = v + bl[0];
    }
}

// ---------------- prefix sum of keep1 (exact int) ----------------
__global__ void k_scan1(const float* __restrict__ keep1, int* __restrict__ prefix,
                        int* __restrict__ bsums) {
    int blk = blockIdx.x, tid = threadIdx.x;
    int base = blk * 1024;
    int vals[4], tsum = 0;
    for (int j = 0; j < 4; ++j) {
        int idx = base + tid * 4 + j;
        int v = (idx < NN && keep1[idx] > 0.f) ? 1 : 0;
        tsum += v; vals[j] = tsum;
    }
    __shared__ int sh[256];
    sh[tid] = tsum; __syncthreads();
    for (int o = 1; o < 256; o <<= 1) {
        int v = (tid >= o) ? sh[tid - o] : 0;
        __syncthreads();
        sh[tid] += v;
        __syncthreads();
    }
    int excl = sh[tid] - tsum;
    for (int j = 0; j < 4; ++j) {
        int idx = base + tid * 4 + j;
        if (idx < NN) prefix[idx] = excl + vals[j];
    }
    if (tid == 255) bsums[blk] = sh[255];
}
__global__ void k_scan2(int* __restrict__ bsums, int nb) {
    int acc = 0;
    for (int i = 0; i < nb; ++i) { int v = bsums[i]; bsums[i] = acc; acc += v; }
}
__global__ void k_scan3(int* __restrict__ prefix, const int* __restrict__ boffs) {
    int idx = blockIdx.x * 256 + threadIdx.x;
    if (idx < NN) prefix[idx] += boffs[idx >> 10];
}

// ---------------- attention KL loss + ratio ----------------
__global__ void k_kl(const float* __restrict__ score2, const float* __restrict__ keep2,
                     const int* __restrict__ prefix, const float* __restrict__ natt,
                     const int* __restrict__ offs, float* __restrict__ out_loss,
                     float* __restrict__ c_total) {
    int b = blockIdx.x, tid = threadIdx.x;
    int s0 = offs[b], s1 = offs[b + 1];
    float s = 0.f, c = 0.f;
    for (int i = s0 + tid; i < s1; i += 256) {
        if (keep2[i] > 0.f) {
            int r1 = prefix[i] - 1;
            r1 = max(0, min(r1, NN - 1));
            float t = natt[r1];
            float logp = logf(score2[i] + 1e-14f);
            float kl = ((t > 0.f) ? t * logf(fmaxf(t, 1e-38f)) : 0.f) - t * logp;
            s += kl; c += 1.f;
        }
    }
    __shared__ float rs[256], rc[256];
    rs[tid] = s; rc[tid] = c; __syncthreads();
    for (int o = 128; o > 0; o >>= 1) {
        if (tid < o) { rs[tid] += rs[tid + o]; rc[tid] += rc[tid + o]; }
        __syncthreads();
    }
    if (tid == 0) {
        out_loss[b] = rs[0] / fmaxf(rc[0], 1.f);
        atomicAdd(c_total, rc[0]);
    }
}
__global__ void k_final(const float* __restrict__ c_total, float* __restrict__ out) {
    out[0] = c_total[0] / (float)NN;
}

extern "C" void kernel_launch(void* const* d_in, const int* in_sizes, int n_in,
                              void* d_out, int out_size, void* d_ws, size_t ws_size,
                              hipStream_t stream) {
    const float* x    = (const float*)d_in[0];
    const int*   src  = (const int*)d_in[1];
    const int*   dst  = (const int*)d_in[2];
    const int*   batch= (const int*)d_in[3];
    const float* natt = (const float*)d_in[4];
    const float* W11 = (const float*)d_in[5],  *b11 = (const float*)d_in[6];
    const float* W12 = (const float*)d_in[7],  *b12 = (const float*)d_in[8];
    const float* gW1 = (const float*)d_in[9],  *gb1 = (const float*)d_in[10];
    const float* W21 = (const float*)d_in[11], *b21 = (const float*)d_in[12];
    const float* W22 = (const float*)d_in[13], *b22 = (const float*)d_in[14];
    const float* gW2 = (const float*)d_in[15], *gb2 = (const float*)d_in[16];
    const float* W31 = (const float*)d_in[17], *b31 = (const float*)d_in[18];
    const float* W32 = (const float*)d_in[19], *b32 = (const float*)d_in[20];
    const float* Wl  = (const float*)d_in[21], *bl  = (const float*)d_in[22];
    float* out = (float*)d_out;

    // workspace layout (hA doubles as h3 after pre3 has consumed... hA is dead post-pre2;
    // h3 written by the final k_post into the hA buffer)
    float* hA     = (float*)d_ws;                 // N*64  (reused as h3)
    float* hB     = hA + (size_t)NN * 64;         // N*64
    float* ybuf   = hB + (size_t)NN * 64;         // N*64
    float* zbuf   = ybuf + (size_t)NN * 64;       // N*64
    float* hwd    = zbuf + (size_t)NN * 64;       // N
    float* dinv   = hwd + NN;                     // N
    float* attn   = dinv + NN;                    // N
    float* score1 = attn + NN;                    // N
    float* keep1  = score1 + NN;                  // N
    float* sk1    = keep1 + NN;                   // N
    float* score2 = sk1 + NN;                     // N
    float* keep2  = score2 + NN;                  // N
    float* sk2    = keep2 + NN;                   // N
    int*   prefix = (int*)(sk2 + NN);             // N
    int*   indeg  = prefix + NN;                  // N
    int*   roffs  = indeg + NN;                   // N+1
    int*   cursor = roffs + NN + 1;               // N (reused as cnt after k_fill)
    int*   csrc   = cursor + NN;                  // E
    int*   offs   = csrc + NE;                    // B+1
    int*   bsums  = offs + NB + 1;                // 128
    float* c_total= (float*)(bsums + 128);        // 1
    int*   cnt    = cursor;                       // alias: cursor dead after k_fill

    const int nblk_n  = (NN + 255) / 256;
    const int nblk_n4 = NN / 4;
    const int nblk_n8 = NN / 8;
    const int nblk_e  = NE / 256;

    // graph offsets (batch sorted -> binary search)
    k_offs_bs<<<2, 256, 0, stream>>>(batch, offs);

    // CSR by dst
    hipMemsetAsync(indeg, 0, NN * sizeof(int), stream);
    k_indeg<<<nblk_e, 256, 0, stream>>>(dst, indeg);
    k_iscan_blk<<<NSCAN_BLK, 256, 0, stream>>>(indeg, roffs, bsums);
    k_iscan_mid<<<1, 1, 0, stream>>>(bsums, NSCAN_BLK, roffs);
    k_iscan_add<<<nblk_n, 256, 0, stream>>>(roffs, bsums, cursor);
    k_fill<<<nblk_e, 256, 0, stream>>>(src, dst, cursor, csrc);

    // ---- GIN1: pre-GEMM + pure gather + post ----
    k_pre1<<<nblk_n4, 256, 0, stream>>>(x, W11, ybuf);
    k_gather_y<<<nblk_n8, 256, 0, stream>>>(ybuf, roffs, csrc, nullptr, nullptr, zbuf, nullptr);
    k_post<<<nblk_n4, 256, 0, stream>>>(zbuf, b11, W12, b12, gW1, indeg, nullptr, nullptr,
                                        hA, hwd, dinv, 1);
    k_attn<<<nblk_n, 256, 0, stream>>>(roffs, csrc, hwd, dinv, gb1, attn);
    k_softmax_pool<<<NB, 256, 0, stream>>>(attn, nullptr, offs, score1, keep1, sk1);

    // ---- GIN2 ----
    k_pre23<<<nblk_n4, 256, 0, stream>>>(hA, sk1, W21, ybuf);
    k_gather_y<<<nblk_n8, 256, 0, stream>>>(ybuf, roffs, csrc, keep1, sk1, zbuf, cnt);
    k_post<<<nblk_n4, 256, 0, stream>>>(zbuf, b21, W22, b22, gW2, nullptr, cnt, keep1,
                                        hB, hwd, dinv, 2);
    k_attn<<<nblk_n, 256, 0, stream>>>(roffs, csrc, hwd, dinv, gb2, attn);
    k_softmax_pool<<<NB, 256, 0, stream>>>(attn, keep1, offs, score2, keep2, sk2);

    // ---- GIN3 (h3 written into hA buffer) ----
    k_pre23<<<nblk_n4, 256, 0, stream>>>(hB, sk2, W31, ybuf);
    k_gather_y<<<nblk_n8, 256, 0, stream>>>(ybuf, roffs, csrc, keep2, nullptr, zbuf, nullptr);
    k_post<<<nblk_n4, 256, 0, stream>>>(zbuf, b31, W32, b32, nullptr, nullptr, nullptr, nullptr,
                                        hA, nullptr, nullptr, 3);

    // ---- head: global max pool + linear ----
    k_gmax_linear<<<NB, 256, 0, stream>>>(hA, keep2, offs, Wl, bl, out);

    // ---- attention KL loss + ratio ----
    k_scan1<<<NSCAN_BLK, 256, 0, stream>>>(keep1, prefix, bsums);
    k_scan2<<<1, 1, 0, stream>>>(bsums, NSCAN_BLK);
    k_scan3<<<nblk_n, 256, 0, stream>>>(prefix, bsums);
    hipMemsetAsync(c_total, 0, sizeof(float), stream);
    k_kl<<<NB, 256, 0, stream>>>(score2, keep2, prefix, natt, offs, out + NB, c_total);
    k_final<<<1, 1, 0, stream>>>(c_total, out + 2 * NB);
}

// Round 8
// 780.668 us; speedup vs baseline: 8.2218x; 1.1689x over previous
//
#include <hip/hip_runtime.h>
#include <math.h>

#define NN 100000
#define NE 1600000
#define NB 256
#define NEGF (-1e30f)
#define NSCAN_BLK ((NN + 1023) / 1024)
#define GVB 1024            // grid-stride GEMV blocks (4096 waves ~= resident capacity)

__device__ __forceinline__ float rlane(float v, int k) {
    return __int_as_float(__builtin_amdgcn_readlane(__float_as_int(v), k));
}

// ---------------- graph offsets via binary search (batch is sorted) ----------------
__global__ void k_offs_bs(const int* __restrict__ batch, int* __restrict__ offs) {
    int g = blockIdx.x * 256 + threadIdx.x;
    if (g > NB) return;
    int lo = 0, hi = NN;
    while (lo < hi) { int mid = (lo + hi) >> 1; if (batch[mid] < g) lo = mid + 1; else hi = mid; }
    offs[g] = lo;
}

// ---------------- CSR (by dst) construction ----------------
__global__ void k_indeg(const int* __restrict__ dst, int* __restrict__ indeg) {
    int e = blockIdx.x * 256 + threadIdx.x;
    if (e < NE) atomicAdd(&indeg[dst[e]], 1);
}
__global__ void k_iscan_blk(const int* __restrict__ in, int* __restrict__ pref,
                            int* __restrict__ bsums) {
    int blk = blockIdx.x, tid = threadIdx.x;
    int base = blk * 1024;
    int vals[4], tsum = 0;
    for (int j = 0; j < 4; ++j) {
        int idx = base + tid * 4 + j;
        int v = (idx < NN) ? in[idx] : 0;
        vals[j] = tsum; tsum += v;               // exclusive within thread
    }
    __shared__ int sh[256];
    sh[tid] = tsum; __syncthreads();
    for (int o = 1; o < 256; o <<= 1) {
        int v = (tid >= o) ? sh[tid - o] : 0;
        __syncthreads();
        sh[tid] += v;
        __syncthreads();
    }
    int excl = sh[tid] - tsum;
    for (int j = 0; j < 4; ++j) {
        int idx = base + tid * 4 + j;
        if (idx < NN) pref[idx] = excl + vals[j];
    }
    if (tid == 255) bsums[blk] = sh[255];
}
__global__ void k_iscan_mid(int* __restrict__ bsums, int nb, int* __restrict__ roffs) {
    int acc = 0;
    for (int i = 0; i < nb; ++i) { int v = bsums[i]; bsums[i] = acc; acc += v; }
    roffs[NN] = NE;
}
__global__ void k_iscan_add(int* __restrict__ pref, const int* __restrict__ bsums,
                            int* __restrict__ cursor) {
    int idx = blockIdx.x * 256 + threadIdx.x;
    if (idx < NN) {
        int v = pref[idx] + bsums[idx >> 10];
        pref[idx] = v;
        cursor[idx] = v;
    }
}
__global__ void k_fill(const int* __restrict__ src, const int* __restrict__ dst,
                       int* __restrict__ cursor, int* __restrict__ csrc) {
    int e = blockIdx.x * 256 + threadIdx.x;
    if (e >= NE) return;
    int p = atomicAdd(&cursor[dst[e]], 1);
    csrc[p] = src[e];
}

// ---------------- GEMV kernels: W column in VGPRs, grid-stride over node tiles ----------------
// pre1: y = x @ W11   (K=128, R=4 rows/wave)
__global__ __launch_bounds__(256, 1) void k_pre1_g(const float* __restrict__ x,
                                                   const float* __restrict__ W,
                                                   float* __restrict__ y) {
    int tid = threadIdx.x, w = tid >> 6, l = tid & 63;
    float Wc[128];
#pragma unroll
    for (int k = 0; k < 128; ++k) Wc[k] = W[k * 64 + l];
    int g = blockIdx.x * 4 + w;
    const int G = GVB * 4;
    for (int t = g; t < NN / 4; t += G) {
        int n0 = t * 4;
        float in0[4], in1[4], acc[4];
#pragma unroll
        for (int r = 0; r < 4; ++r) {
            in0[r] = x[(size_t)(n0 + r) * 128 + l];
            in1[r] = x[(size_t)(n0 + r) * 128 + 64 + l];
            acc[r] = 0.f;
        }
#pragma unroll
        for (int k = 0; k < 64; ++k)
#pragma unroll
            for (int r = 0; r < 4; ++r) acc[r] = fmaf(rlane(in0[r], k), Wc[k], acc[r]);
#pragma unroll
        for (int k = 0; k < 64; ++k)
#pragma unroll
            for (int r = 0; r < 4; ++r) acc[r] = fmaf(rlane(in1[r], k), Wc[64 + k], acc[r]);
#pragma unroll
        for (int r = 0; r < 4; ++r) y[(size_t)(n0 + r) * 64 + l] = acc[r];
    }
}

// pre23: y = (h * sk) @ W   (K=64, R=8)
__global__ __launch_bounds__(256) void k_pre23_g(const float* __restrict__ h,
                                                 const float* __restrict__ sk,
                                                 const float* __restrict__ W,
                                                 float* __restrict__ y) {
    int tid = threadIdx.x, w = tid >> 6, l = tid & 63;
    float Wc[64];
#pragma unroll
    for (int k = 0; k < 64; ++k) Wc[k] = W[k * 64 + l];
    int g = blockIdx.x * 4 + w;
    const int G = GVB * 4;
    for (int t = g; t < NN / 8; t += G) {
        int n0 = t * 8;
        float in[8], acc[8];
#pragma unroll
        for (int r = 0; r < 8; ++r) {
            in[r] = h[(size_t)(n0 + r) * 64 + l] * sk[n0 + r];
            acc[r] = 0.f;
        }
#pragma unroll
        for (int k = 0; k < 64; ++k)
#pragma unroll
            for (int r = 0; r < 8; ++r) acc[r] = fmaf(rlane(in[r], k), Wc[k], acc[r]);
#pragma unroll
        for (int r = 0; r < 8; ++r) y[(size_t)(n0 + r) * 64 + l] = acc[r];
    }
}

// post: h = relu(relu(z+b1)@W2 + b2) [+ score-dot + dinv epilogue]  (K=64, R=8)
// mode 1: dinv from indeg (pool1). mode 2: dinv from cnt & keep (pool2). mode 3: none.
__global__ __launch_bounds__(256) void k_post_g(const float* __restrict__ z,
                                                const float* __restrict__ b1,
                                                const float* __restrict__ W2,
                                                const float* __restrict__ b2,
                                                const float* __restrict__ gW,
                                                const int* __restrict__ indeg,
                                                const int* __restrict__ cnt,
                                                const float* __restrict__ keep,
                                                float* __restrict__ hOut,
                                                float* __restrict__ hwd,
                                                float* __restrict__ dinv, int mode) {
    int tid = threadIdx.x, w = tid >> 6, l = tid & 63;
    float Wc[64];
#pragma unroll
    for (int k = 0; k < 64; ++k) Wc[k] = W2[k * 64 + l];
    float b1v = b1[l], b2v = b2[l];
    float gWv = (mode < 3) ? gW[l] : 0.f;
    int g = blockIdx.x * 4 + w;
    const int G = GVB * 4;
    for (int t = g; t < NN / 8; t += G) {
        int n0 = t * 8;
        float in[8], acc[8];
#pragma unroll
        for (int r = 0; r < 8; ++r) {
            in[r] = fmaxf(z[(size_t)(n0 + r) * 64 + l] + b1v, 0.f);
            acc[r] = b2v;
        }
#pragma unroll
        for (int k = 0; k < 64; ++k)
#pragma unroll
            for (int r = 0; r < 8; ++r) acc[r] = fmaf(rlane(in[r], k), Wc[k], acc[r]);
#pragma unroll
        for (int r = 0; r < 8; ++r) {
            acc[r] = fmaxf(acc[r], 0.f);
            hOut[(size_t)(n0 + r) * 64 + l] = acc[r];
        }
        if (mode < 3) {
#pragma unroll
            for (int r = 0; r < 8; ++r) {
                float t2 = acc[r] * gWv;
                for (int o = 32; o > 0; o >>= 1) t2 += __shfl_down(t2, o, 64);
                if (l == 0) {
                    int n = n0 + r;
                    float di;
                    if (mode == 1) di = 1.f / sqrtf((float)indeg[n] + 1.f);
                    else di = (keep[n] != 0.f) ? 1.f / sqrtf((float)cnt[n] + 1.f) : 0.f;
                    dinv[n] = di;
                    hwd[n] = t2 * di;
                }
            }
        }
    }
}

// ---------------- pure CSR gather of transformed rows: z[d] = y[d] + [gate] sum y[s] ----------
__global__ void k_gather_y(const float* __restrict__ y, const int* __restrict__ roffs,
                           const int* __restrict__ csrc, const float* __restrict__ keepd,
                           const float* __restrict__ sk, float* __restrict__ z,
                           int* __restrict__ cnt) {
    int tid = threadIdx.x;
    int d = blockIdx.x * 8 + (tid >> 5);
    int l = tid & 31;
    const float2* y2 = (const float2*)y;
    float2 acc = y2[(size_t)d * 32 + l];            // self term
    int c = 0;
    if (!keepd || keepd[d] != 0.f) {                // dst-side gate (wave-uniform)
        int e0 = roffs[d], e1 = roffs[d + 1];
        int e = e0;
        for (; e + 1 < e1; e += 2) {
            int s0 = csrc[e], s1 = csrc[e + 1];
            float2 v0 = y2[(size_t)s0 * 32 + l];
            float2 v1 = y2[(size_t)s1 * 32 + l];
            acc.x += v0.x + v1.x; acc.y += v0.y + v1.y;
            if (sk) c += (sk[s0] > 0.f) + (sk[s1] > 0.f);
        }
        if (e < e1) {
            int s0 = csrc[e];
            float2 v0 = y2[(size_t)s0 * 32 + l];
            acc.x += v0.x; acc.y += v0.y;
            if (sk) c += (sk[s0] > 0.f);
        }
    }
    ((float2*)z)[(size_t)d * 32 + l] = acc;
    if (cnt && l == 0) cnt[d] = c;
}

// ---------------- attention gather: attn[i] = dinv[i]*(sum_nbr hwd + hwd[i]) + gb ----------------
__global__ void k_attn(const int* __restrict__ roffs, const int* __restrict__ csrc,
                       const float* __restrict__ hwd, const float* __restrict__ dinv,
                       const float* __restrict__ gb, float* __restrict__ attn) {
    int i = blockIdx.x * 256 + threadIdx.x;
    if (i >= NN) return;
    float sum = hwd[i];
    int e0 = roffs[i], e1 = roffs[i + 1];
    for (int e = e0; e < e1; ++e) sum += hwd[csrc[e]];
    attn[i] = dinv[i] * sum + gb[0];
}

// ---------------- per-graph softmax + threshold; also emits sk = score*keep ----------------
__global__ void k_softmax_pool(const float* __restrict__ attn, const float* __restrict__ nmask,
                               const int* __restrict__ offs, float* __restrict__ score,
                               float* __restrict__ keep, float* __restrict__ sk) {
    int b = blockIdx.x, tid = threadIdx.x;
    int s0 = offs[b], s1 = offs[b + 1];
    __shared__ float red[256];
    float m = NEGF;
    for (int i = s0 + tid; i < s1; i += 256) {
        float nm = nmask ? nmask[i] : 1.f;
        if (nm > 0.f) m = fmaxf(m, attn[i]);
    }
    red[tid] = m; __syncthreads();
    for (int o = 128; o > 0; o >>= 1) { if (tid < o) red[tid] = fmaxf(red[tid], red[tid + o]); __syncthreads(); }
    m = red[0]; __syncthreads();
    float s = 0.f;
    for (int i = s0 + tid; i < s1; i += 256) {
        float nm = nmask ? nmask[i] : 1.f;
        if (nm > 0.f) s += expf(attn[i] - m);
    }
    red[tid] = s; __syncthreads();
    for (int o = 128; o > 0; o >>= 1) { if (tid < o) red[tid] += red[tid + o]; __syncthreads(); }
    s = red[0]; __syncthreads();
    float sden = fmaxf(s, 1e-30f);
    float smax = NEGF;
    for (int i = s0 + tid; i < s1; i += 256) {
        float nm = nmask ? nmask[i] : 1.f;
        float sc = (nm > 0.f) ? expf(attn[i] - m) / sden : 0.f;
        score[i] = sc;
        smax = fmaxf(smax, (nm > 0.f) ? sc : NEGF);
    }
    red[tid] = smax; __syncthreads();
    for (int o = 128; o > 0; o >>= 1) { if (tid < o) red[tid] = fmaxf(red[tid], red[tid + o]); __syncthreads(); }
    smax = red[0]; __syncthreads();
    float thr = fminf(1e-3f, smax - 1e-7f);
    for (int i = s0 + tid; i < s1; i += 256) {
        float nm = nmask ? nmask[i] : 1.f;
        float sc = score[i];
        float kp = (nm > 0.f && sc > thr) ? 1.f : 0.f;
        keep[i] = kp;
        sk[i] = sc * kp;
    }
}

// ---------------- output head ----------------
__global__ void k_gmax_linear(const float* __restrict__ h, const float* __restrict__ keep2,
                              const int* __restrict__ offs, const float* __restrict__ Wl,
                              const float* __restrict__ bl, float* __restrict__ out) {
    int b = blockIdx.x, tid = threadIdx.x;
    int s0 = offs[b], s1 = offs[b + 1];
    int f = tid & 63, g = tid >> 6;
    float m = NEGF;
    for (int i = s0 + g; i < s1; i += 4)
        if (keep2[i] > 0.f) m = fmaxf(m, h[(size_t)i * 64 + f]);
    __shared__ float red[256];
    red[tid] = m; __syncthreads();
    if (g == 0) {
        m = fmaxf(fmaxf(red[f], red[64 + f]), fmaxf(red[128 + f], red[192 + f]));
        float v = m * Wl[f];
        for (int o = 32; o > 0; o >>= 1) v += __shfl_down(v, o, 64);
        if (f == 0) out[b] = v + bl[0];
    }
}

// ---------------- prefix sum of keep1 (exact int) ----------------
__global__ void k_scan1(const float* __restrict__ keep1, int* __restrict__ prefix,
                        int* __restrict__ bsums) {
    int blk = blockIdx.x, tid = threadIdx.x;
    int base = blk * 1024;
    int vals[4], tsum = 0;
    for (int j = 0; j < 4; ++j) {
        int idx = base + tid * 4 + j;
        int v = (idx < NN && keep1[idx] > 0.f) ? 1 : 0;
        tsum += v; vals[j] = tsum;
    }
    __shared__ int sh[256];
    sh[tid] = tsum; __syncthreads();
    for (int o = 1; o < 256; o <<= 1) {
        int v = (tid >= o) ? sh[tid - o] : 0;
        __syncthreads();
        sh[tid] += v;
        __syncthreads();
    }
    int excl = sh[tid] - tsum;
    for (int j = 0; j < 4; ++j) {
        int idx = base + tid * 4 + j;
        if (idx < NN) prefix[idx] = excl + vals[j];
    }
    if (tid == 255) bsums[blk] = sh[255];
}
__global__ void k_scan2(int* __restrict__ bsums, int nb) {
    int acc = 0;
    for (int i = 0; i < nb; ++i) { int v = bsums[i]; bsums[i] = acc; acc += v; }
}
__global__ void k_scan3(int* __restrict__ prefix, const int* __restrict__ boffs) {
    int idx = blockIdx.x * 256 + threadIdx.x;
    if (idx < NN) prefix[idx] += boffs[idx >> 10];
}

// ---------------- attention KL loss + ratio ----------------
__global__ void k_kl(const float* __restrict__ score2, const float* __restrict__ keep2,
                     const int* __restrict__ prefix, const float* __restrict__ natt,
                     const int* __restrict__ offs, float* __restrict__ out_loss,
                     float* __restrict__ c_total) {
    int b = blockIdx.x, tid = threadIdx.x;
    int s0 = offs[b], s1 = offs[b + 1];
    float s = 0.f, c = 0.f;
    for (int i = s0 + tid; i < s1; i += 256) {
        if (keep2[i] > 0.f) {
            int r1 = prefix[i] - 1;
            r1 = max(0, min(r1, NN - 1));
            float t = natt[r1];
            float logp = logf(score2[i] + 1e-14f);
            float kl = ((t > 0.f) ? t * logf(fmaxf(t, 1e-38f)) : 0.f) - t * logp;
            s += kl; c += 1.f;
        }
    }
    __shared__ float rs[256], rc[256];
    rs[tid] = s; rc[tid] = c; __syncthreads();
    for (int o = 128; o > 0; o >>= 1) {
        if (tid < o) { rs[tid] += rs[tid + o]; rc[tid] += rc[tid + o]; }
        __syncthreads();
    }
    if (tid == 0) {
        out_loss[b] = rs[0] / fmaxf(rc[0], 1.f);
        atomicAdd(c_total, rc[0]);
    }
}
__global__ void k_final(const float* __restrict__ c_total, float* __restrict__ out) {
    out[0] = c_total[0] / (float)NN;
}

extern "C" void kernel_launch(void* const* d_in, const int* in_sizes, int n_in,
                              void* d_out, int out_size, void* d_ws, size_t ws_size,
                              hipStream_t stream) {
    const float* x    = (const float*)d_in[0];
    const int*   src  = (const int*)d_in[1];
    const int*   dst  = (const int*)d_in[2];
    const int*   batch= (const int*)d_in[3];
    const float* natt = (const float*)d_in[4];
    const float* W11 = (const float*)d_in[5],  *b11 = (const float*)d_in[6];
    const float* W12 = (const float*)d_in[7],  *b12 = (const float*)d_in[8];
    const float* gW1 = (const float*)d_in[9],  *gb1 = (const float*)d_in[10];
    const float* W21 = (const float*)d_in[11], *b21 = (const float*)d_in[12];
    const float* W22 = (const float*)d_in[13], *b22 = (const float*)d_in[14];
    const float* gW2 = (const float*)d_in[15], *gb2 = (const float*)d_in[16];
    const float* W31 = (const float*)d_in[17], *b31 = (const float*)d_in[18];
    const float* W32 = (const float*)d_in[19], *b32 = (const float*)d_in[20];
    const float* Wl  = (const float*)d_in[21], *bl  = (const float*)d_in[22];
    float* out = (float*)d_out;

    // workspace layout
    float* hA     = (float*)d_ws;                 // N*64  (reused as h3)
    float* hB     = hA + (size_t)NN * 64;         // N*64
    float* ybuf   = hB + (size_t)NN * 64;         // N*64
    float* zbuf   = ybuf + (size_t)NN * 64;       // N*64
    float* hwd    = zbuf + (size_t)NN * 64;       // N
    float* dinv   = hwd + NN;                     // N
    float* attn   = dinv + NN;                    // N
    float* score1 = attn + NN;                    // N
    float* keep1  = score1 + NN;                  // N
    float* sk1    = keep1 + NN;                   // N
    float* score2 = sk1 + NN;                     // N
    float* keep2  = score2 + NN;                  // N
    float* sk2    = keep2 + NN;                   // N
    int*   prefix = (int*)(sk2 + NN);             // N
    int*   indeg  = prefix + NN;                  // N
    int*   roffs  = indeg + NN;                   // N+1
    int*   cursor = roffs + NN + 1;               // N (reused as cnt after k_fill)
    int*   csrc   = cursor + NN;                  // E
    int*   offs   = csrc + NE;                    // B+1
    int*   bsums  = offs + NB + 1;                // 128
    float* c_total= (float*)(bsums + 128);        // 1
    int*   cnt    = cursor;                       // alias: cursor dead after k_fill

    const int nblk_n  = (NN + 255) / 256;
    const int nblk_n8 = NN / 8;
    const int nblk_e  = NE / 256;

    // graph offsets (batch sorted -> binary search)
    k_offs_bs<<<2, 256, 0, stream>>>(batch, offs);

    // CSR by dst
    hipMemsetAsync(indeg, 0, NN * sizeof(int), stream);
    k_indeg<<<nblk_e, 256, 0, stream>>>(dst, indeg);
    k_iscan_blk<<<NSCAN_BLK, 256, 0, stream>>>(indeg, roffs, bsums);
    k_iscan_mid<<<1, 1, 0, stream>>>(bsums, NSCAN_BLK, roffs);
    k_iscan_add<<<nblk_n, 256, 0, stream>>>(roffs, bsums, cursor);
    k_fill<<<nblk_e, 256, 0, stream>>>(src, dst, cursor, csrc);

    // ---- GIN1: pre-GEMM + pure gather + post ----
    k_pre1_g<<<GVB, 256, 0, stream>>>(x, W11, ybuf);
    k_gather_y<<<nblk_n8, 256, 0, stream>>>(ybuf, roffs, csrc, nullptr, nullptr, zbuf, nullptr);
    k_post_g<<<GVB, 256, 0, stream>>>(zbuf, b11, W12, b12, gW1, indeg, nullptr, nullptr,
                                      hA, hwd, dinv, 1);
    k_attn<<<nblk_n, 256, 0, stream>>>(roffs, csrc, hwd, dinv, gb1, attn);
    k_softmax_pool<<<NB, 256, 0, stream>>>(attn, nullptr, offs, score1, keep1, sk1);

    // ---- GIN2 ----
    k_pre23_g<<<GVB, 256, 0, stream>>>(hA, sk1, W21, ybuf);
    k_gather_y<<<nblk_n8, 256, 0, stream>>>(ybuf, roffs, csrc, keep1, sk1, zbuf, cnt);
    k_post_g<<<GVB, 256, 0, stream>>>(zbuf, b21, W22, b22, gW2, nullptr, cnt, keep1,
                                      hB, hwd, dinv, 2);
    k_attn<<<nblk_n, 256, 0, stream>>>(roffs, csrc, hwd, dinv, gb2, attn);
    k_softmax_pool<<<NB, 256, 0, stream>>>(attn, keep1, offs, score2, keep2, sk2);

    // ---- GIN3 (h3 written into hA buffer) ----
    k_pre23_g<<<GVB, 256, 0, stream>>>(hB, sk2, W31, ybuf);
    k_gather_y<<<nblk_n8, 256, 0, stream>>>(ybuf, roffs, csrc, keep2, nullptr, zbuf, nullptr);
    k_post_g<<<GVB, 256, 0, stream>>>(zbuf, b31, W32, b32, nullptr, nullptr, nullptr, nullptr,
                                      hA, nullptr, nullptr, 3);

    // ---- head: global max pool + linear ----
    k_gmax_linear<<<NB, 256, 0, stream>>>(hA, keep2, offs, Wl, bl, out);

    // ---- attention KL loss + ratio ----
    k_scan1<<<NSCAN_BLK, 256, 0, stream>>>(keep1, prefix, bsums);
    k_scan2<<<1, 1, 0, stream>>>(bsums, NSCAN_BLK);
    k_scan3<<<nblk_n, 256, 0, stream>>>(prefix, bsums);
    hipMemsetAsync(c_total, 0, sizeof(float), stream);
    k_kl<<<NB, 256, 0, stream>>>(score2, keep2, prefix, natt, offs, out + NB, c_total);
    k_final<<<1, 1, 0, stream>>>(c_total, out + 2 * NB);
}

// Round 9
// 632.068 us; speedup vs baseline: 10.1547x; 1.2351x over previous
//
#include <hip/hip_runtime.h>
#include <math.h>

#define NN 100000
#define NE 1600000
#define NB 256
#define NEGF (-1e30f)
#define NSCAN_BLK ((NN + 1023) / 1024)
#define GVB 1024            // grid-stride GEMV blocks
#define P_SORT 256          // blocks in coarse histogram/scatter
#define NBKT 391            // ceil(NN/256) coarse buckets (dst>>8)
#define HLEN (NBKT * P_SORT)
#define HSCAN_BLK ((HLEN + 1023) / 1024)
#define BKT_CAP 6144        // LDS staging ints (24 KB); avg bucket = 4096 edges

__device__ __forceinline__ float rlane(float v, int k) {
    return __int_as_float(__builtin_amdgcn_readlane(__float_as_int(v), k));
}

// ---------------- graph offsets via binary search (batch is sorted) ----------------
__global__ void k_offs_bs(const int* __restrict__ batch, int* __restrict__ offs) {
    int g = blockIdx.x * 256 + threadIdx.x;
    if (g > NB) return;
    int lo = 0, hi = NN;
    while (lo < hi) { int mid = (lo + hi) >> 1; if (batch[mid] < g) lo = mid + 1; else hi = mid; }
    offs[g] = lo;
}

// ---------------- CSR build: two-level counting sort (no global scatter amplification) ----
// phase 1: per-block coarse histogram over dst>>8
__global__ void k_hist_coarse(const int* __restrict__ dst, int* __restrict__ H) {
    __shared__ int lh[NBKT];
    int p = blockIdx.x, tid = threadIdx.x;
    for (int i = tid; i < NBKT; i += 256) lh[i] = 0;
    __syncthreads();
    int c0 = p * (NE / P_SORT), c1 = c0 + NE / P_SORT;
    for (int i = c0 + tid; i < c1; i += 256) atomicAdd(&lh[dst[i] >> 8], 1);
    __syncthreads();
    for (int i = tid; i < NBKT; i += 256) H[i * P_SORT + p] = lh[i];
}
// generic hierarchical exclusive scan (len <= 128*1024)
__global__ void k_iscan_blk(const int* __restrict__ in, int* __restrict__ pref,
                            int* __restrict__ bsums, int len) {
    int blk = blockIdx.x, tid = threadIdx.x;
    int base = blk * 1024;
    int vals[4], tsum = 0;
    for (int j = 0; j < 4; ++j) {
        int idx = base + tid * 4 + j;
        int v = (idx < len) ? in[idx] : 0;
        vals[j] = tsum; tsum += v;               // exclusive within thread
    }
    __shared__ int sh[256];
    sh[tid] = tsum; __syncthreads();
    for (int o = 1; o < 256; o <<= 1) {
        int v = (tid >= o) ? sh[tid - o] : 0;
        __syncthreads();
        sh[tid] += v;
        __syncthreads();
    }
    int excl = sh[tid] - tsum;
    for (int j = 0; j < 4; ++j) {
        int idx = base + tid * 4 + j;
        if (idx < len) pref[idx] = excl + vals[j];
    }
    if (tid == 255) bsums[blk] = sh[255];
}
__global__ void k_iscan_mid(int* __restrict__ bsums, int nb) {
    int acc = 0;
    for (int i = 0; i < nb; ++i) { int v = bsums[i]; bsums[i] = acc; acc += v; }
}
__global__ void k_iscan_add(int* __restrict__ pref, const int* __restrict__ bsums, int len) {
    int idx = blockIdx.x * 256 + threadIdx.x;
    if (idx < len) pref[idx] += bsums[idx >> 10];
}
// phase 3: scatter (src,dst) pairs into per-(bucket,block) exclusive contiguous ranges
__global__ void k_scatter_pairs(const int* __restrict__ src, const int* __restrict__ dst,
                                const int* __restrict__ Hs, int2* __restrict__ ebuf) {
    __shared__ int curs[NBKT];
    int p = blockIdx.x, tid = threadIdx.x;
    for (int i = tid; i < NBKT; i += 256) curs[i] = Hs[i * P_SORT + p];
    __syncthreads();
    int c0 = p * (NE / P_SORT), c1 = c0 + NE / P_SORT;
    for (int i = c0 + tid; i < c1; i += 256) {
        int d = dst[i];
        int pos = atomicAdd(&curs[d >> 8], 1);
        ebuf[pos] = make_int2(src[i], d);
    }
}
// phase 4: per-bucket fine CSR: roffs + LDS-staged csrc (coalesced global writes)
__global__ void k_bucket_csr(const int2* __restrict__ ebuf, const int* __restrict__ Hs,
                             int* __restrict__ roffs, int* __restrict__ csrc) {
    __shared__ int hist2[256];
    __shared__ int curs2[256];
    __shared__ int sh[256];
    __shared__ int stage[BKT_CAP];
    int b = blockIdx.x, tid = threadIdx.x;
    int e0 = Hs[b * P_SORT];
    int e1 = (b + 1 < NBKT) ? Hs[(b + 1) * P_SORT] : NE;
    int n0 = b * 256;
    int cntb = e1 - e0;
    if (b == 0 && tid == 0) roffs[NN] = NE;
    hist2[tid] = 0;
    __syncthreads();
    for (int i = e0 + tid; i < e1; i += 256) atomicAdd(&hist2[ebuf[i].y & 255], 1);
    __syncthreads();
    int v = hist2[tid];
    sh[tid] = v; __syncthreads();
    for (int o = 1; o < 256; o <<= 1) {
        int u = (tid >= o) ? sh[tid - o] : 0;
        __syncthreads();
        sh[tid] += u;
        __syncthreads();
    }
    int excl = sh[tid] - v;
    int node = n0 + tid;
    if (node < NN) roffs[node] = e0 + excl;
    curs2[tid] = excl;
    __syncthreads();
    if (cntb <= BKT_CAP) {
        for (int i = e0 + tid; i < e1; i += 256) {
            int2 pr = ebuf[i];
            int pos = atomicAdd(&curs2[pr.y & 255], 1);
            stage[pos] = pr.x;
        }
        __syncthreads();
        for (int i = tid; i < cntb; i += 256) csrc[e0 + i] = stage[i];
    } else {                                     // improbable overflow fallback
        for (int i = e0 + tid; i < e1; i += 256) {
            int2 pr = ebuf[i];
            int pos = atomicAdd(&curs2[pr.y & 255], 1);
            csrc[e0 + pos] = pr.x;
        }
    }
}

// ---------------- GEMV kernels: W column in VGPRs, grid-stride over node tiles ----------------
__global__ __launch_bounds__(256, 1) void k_pre1_g(const float* __restrict__ x,
                                                   const float* __restrict__ W,
                                                   float* __restrict__ y) {
    int tid = threadIdx.x, w = tid >> 6, l = tid & 63;
    float Wc[128];
#pragma unroll
    for (int k = 0; k < 128; ++k) Wc[k] = W[k * 64 + l];
    int g = blockIdx.x * 4 + w;
    const int G = GVB * 4;
    for (int t = g; t < NN / 4; t += G) {
        int n0 = t * 4;
        float in0[4], in1[4], acc[4];
#pragma unroll
        for (int r = 0; r < 4; ++r) {
            in0[r] = x[(size_t)(n0 + r) * 128 + l];
            in1[r] = x[(size_t)(n0 + r) * 128 + 64 + l];
            acc[r] = 0.f;
        }
#pragma unroll
        for (int k = 0; k < 64; ++k)
#pragma unroll
            for (int r = 0; r < 4; ++r) acc[r] = fmaf(rlane(in0[r], k), Wc[k], acc[r]);
#pragma unroll
        for (int k = 0; k < 64; ++k)
#pragma unroll
            for (int r = 0; r < 4; ++r) acc[r] = fmaf(rlane(in1[r], k), Wc[64 + k], acc[r]);
#pragma unroll
        for (int r = 0; r < 4; ++r) y[(size_t)(n0 + r) * 64 + l] = acc[r];
    }
}

__global__ __launch_bounds__(256) void k_pre23_g(const float* __restrict__ h,
                                                 const float* __restrict__ sk,
                                                 const float* __restrict__ W,
                                                 float* __restrict__ y) {
    int tid = threadIdx.x, w = tid >> 6, l = tid & 63;
    float Wc[64];
#pragma unroll
    for (int k = 0; k < 64; ++k) Wc[k] = W[k * 64 + l];
    int g = blockIdx.x * 4 + w;
    const int G = GVB * 4;
    for (int t = g; t < NN / 8; t += G) {
        int n0 = t * 8;
        float in[8], acc[8];
#pragma unroll
        for (int r = 0; r < 8; ++r) {
            in[r] = h[(size_t)(n0 + r) * 64 + l] * sk[n0 + r];
            acc[r] = 0.f;
        }
#pragma unroll
        for (int k = 0; k < 64; ++k)
#pragma unroll
            for (int r = 0; r < 8; ++r) acc[r] = fmaf(rlane(in[r], k), Wc[k], acc[r]);
#pragma unroll
        for (int r = 0; r < 8; ++r) y[(size_t)(n0 + r) * 64 + l] = acc[r];
    }
}

// post: h = relu(relu(z+b1)@W2 + b2) [+ score-dot + dinv epilogue]
// mode 1: dinv from roffs-degree (pool1). mode 2: dinv from cnt & keep (pool2). mode 3: none.
__global__ __launch_bounds__(256) void k_post_g(const float* __restrict__ z,
                                                const float* __restrict__ b1,
                                                const float* __restrict__ W2,
                                                const float* __restrict__ b2,
                                                const float* __restrict__ gW,
                                                const int* __restrict__ roffs,
                                                const int* __restrict__ cnt,
                                                const float* __restrict__ keep,
                                                float* __restrict__ hOut,
                                                float* __restrict__ hwd,
                                                float* __restrict__ dinv, int mode) {
    int tid = threadIdx.x, w = tid >> 6, l = tid & 63;
    float Wc[64];
#pragma unroll
    for (int k = 0; k < 64; ++k) Wc[k] = W2[k * 64 + l];
    float b1v = b1[l], b2v = b2[l];
    float gWv = (mode < 3) ? gW[l] : 0.f;
    int g = blockIdx.x * 4 + w;
    const int G = GVB * 4;
    for (int t = g; t < NN / 8; t += G) {
        int n0 = t * 8;
        float in[8], acc[8];
#pragma unroll
        for (int r = 0; r < 8; ++r) {
            in[r] = fmaxf(z[(size_t)(n0 + r) * 64 + l] + b1v, 0.f);
            acc[r] = b2v;
        }
#pragma unroll
        for (int k = 0; k < 64; ++k)
#pragma unroll
            for (int r = 0; r < 8; ++r) acc[r] = fmaf(rlane(in[r], k), Wc[k], acc[r]);
#pragma unroll
        for (int r = 0; r < 8; ++r) {
            acc[r] = fmaxf(acc[r], 0.f);
            hOut[(size_t)(n0 + r) * 64 + l] = acc[r];
        }
        if (mode < 3) {
#pragma unroll
            for (int r = 0; r < 8; ++r) {
                float t2 = acc[r] * gWv;
                for (int o = 32; o > 0; o >>= 1) t2 += __shfl_down(t2, o, 64);
                if (l == 0) {
                    int n = n0 + r;
                    float di;
                    if (mode == 1) di = 1.f / sqrtf((float)(roffs[n + 1] - roffs[n]) + 1.f);
                    else di = (keep[n] != 0.f) ? 1.f / sqrtf((float)cnt[n] + 1.f) : 0.f;
                    dinv[n] = di;
                    hwd[n] = t2 * di;
                }
            }
        }
    }
}

// ---------------- pure CSR gather of transformed rows: z[d] = y[d] + [gate] sum y[s] ----------
__global__ void k_gather_y(const float* __restrict__ y, const int* __restrict__ roffs,
                           const int* __restrict__ csrc, const float* __restrict__ keepd,
                           const float* __restrict__ sk, float* __restrict__ z,
                           int* __restrict__ cnt) {
    int tid = threadIdx.x;
    int d = blockIdx.x * 8 + (tid >> 5);
    int l = tid & 31;
    const float2* y2 = (const float2*)y;
    float2 acc = y2[(size_t)d * 32 + l];            // self term
    int c = 0;
    if (!keepd || keepd[d] != 0.f) {                // dst-side gate (wave-uniform)
        int e0 = roffs[d], e1 = roffs[d + 1];
        int e = e0;
        for (; e + 1 < e1; e += 2) {
            int s0 = csrc[e], s1 = csrc[e + 1];
            float2 v0 = y2[(size_t)s0 * 32 + l];
            float2 v1 = y2[(size_t)s1 * 32 + l];
            acc.x += v0.x + v1.x; acc.y += v0.y + v1.y;
            if (sk) c += (sk[s0] > 0.f) + (sk[s1] > 0.f);
        }
        if (e < e1) {
            int s0 = csrc[e];
            float2 v0 = y2[(size_t)s0 * 32 + l];
            acc.x += v0.x; acc.y += v0.y;
            if (sk) c += (sk[s0] > 0.f);
        }
    }
    ((float2*)z)[(size_t)d * 32 + l] = acc;
    if (cnt && l == 0) cnt[d] = c;
}

// ---------------- attention gather: attn[i] = dinv[i]*(sum_nbr hwd + hwd[i]) + gb ----------------
__global__ void k_attn(const int* __restrict__ roffs, const int* __restrict__ csrc,
                       const float* __restrict__ hwd, const float* __restrict__ dinv,
                       const float* __restrict__ gb, float* __restrict__ attn) {
    int i = blockIdx.x * 256 + threadIdx.x;
    if (i >= NN) return;
    float sum = hwd[i];
    int e0 = roffs[i], e1 = roffs[i + 1];
    for (int e = e0; e < e1; ++e) sum += hwd[csrc[e]];
    attn[i] = dinv[i] * sum + gb[0];
}

// ---------------- per-graph softmax + threshold; also emits sk = score*keep ----------------
__global__ void k_softmax_pool(const float* __restrict__ attn, const float* __restrict__ nmask,
                               const int* __restrict__ offs, float* __restrict__ score,
                               float* __restrict__ keep, float* __restrict__ sk) {
    int b = blockIdx.x, tid = threadIdx.x;
    int s0 = offs[b], s1 = offs[b + 1];
    __shared__ float red[256];
    float m = NEGF;
    for (int i = s0 + tid; i < s1; i += 256) {
        float nm = nmask ? nmask[i] : 1.f;
        if (nm > 0.f) m = fmaxf(m, attn[i]);
    }
    red[tid] = m; __syncthreads();
    for (int o = 128; o > 0; o >>= 1) { if (tid < o) red[tid] = fmaxf(red[tid], red[tid + o]); __syncthreads(); }
    m = red[0]; __syncthreads();
    float s = 0.f;
    for (int i = s0 + tid; i < s1; i += 256) {
        float nm = nmask ? nmask[i] : 1.f;
        if (nm > 0.f) s += expf(attn[i] - m);
    }
    red[tid] = s; __syncthreads();
    for (int o = 128; o > 0; o >>= 1) { if (tid < o) red[tid] += red[tid + o]; __syncthreads(); }
    s = red[0]; __syncthreads();
    float sden = fmaxf(s, 1e-30f);
    float smax = NEGF;
    for (int i = s0 + tid; i < s1; i += 256) {
        float nm = nmask ? nmask[i] : 1.f;
        float sc = (nm > 0.f) ? expf(attn[i] - m) / sden : 0.f;
        score[i] = sc;
        smax = fmaxf(smax, (nm > 0.f) ? sc : NEGF);
    }
    red[tid] = smax; __syncthreads();
    for (int o = 128; o > 0; o >>= 1) { if (tid < o) red[tid] = fmaxf(red[tid], red[tid + o]); __syncthreads(); }
    smax = red[0]; __syncthreads();
    float thr = fminf(1e-3f, smax - 1e-7f);
    for (int i = s0 + tid; i < s1; i += 256) {
        float nm = nmask ? nmask[i] : 1.f;
        float sc = score[i];
        float kp = (nm > 0.f && sc > thr) ? 1.f : 0.f;
        keep[i] = kp;
        sk[i] = sc * kp;
    }
}

// ---------------- output head ----------------
__global__ void k_gmax_linear(const float* __restrict__ h, const float* __restrict__ keep2,
                              const int* __restrict__ offs, const float* __restrict__ Wl,
                              const float* __restrict__ bl, float* __restrict__ out) {
    int b = blockIdx.x, tid = threadIdx.x;
    int s0 = offs[b], s1 = offs[b + 1];
    int f = tid & 63, g = tid >> 6;
    float m = NEGF;
    for (int i = s0 + g; i < s1; i += 4)
        if (keep2[i] > 0.f) m = fmaxf(m, h[(size_t)i * 64 + f]);
    __shared__ float red[256];
    red[tid] = m; __syncthreads();
    if (g == 0) {
        m = fmaxf(fmaxf(red[f], red[64 + f]), fmaxf(red[128 + f], red[192 + f]));
        float v = m * Wl[f];
        for (int o = 32; o > 0; o >>= 1) v += __shfl_down(v, o, 64);
        if (f == 0) out[b] = v + bl[0];
    }
}

// ---------------- prefix sum of keep1 (exact int) ----------------
__global__ void k_scan1(const float* __restrict__ keep1, int* __restrict__ prefix,
                        int* __restrict__ bsums) {
    int blk = blockIdx.x, tid = threadIdx.x;
    int base = blk * 1024;
    int vals[4], tsum = 0;
    for (int j = 0; j < 4; ++j) {
        int idx = base + tid * 4 + j;
        int v = (idx < NN && keep1[idx] > 0.f) ? 1 : 0;
        tsum += v; vals[j] = tsum;
    }
    __shared__ int sh[256];
    sh[tid] = tsum; __syncthreads();
    for (int o = 1; o < 256; o <<= 1) {
        int v = (tid >= o) ? sh[tid - o] : 0;
        __syncthreads();
        sh[tid] += v;
        __syncthreads();
    }
    int excl = sh[tid] - tsum;
    for (int j = 0; j < 4; ++j) {
        int idx = base + tid * 4 + j;
        if (idx < NN) prefix[idx] = excl + vals[j];
    }
    if (tid == 255) bsums[blk] = sh[255];
}
__global__ void k_scan3(int* __restrict__ prefix, const int* __restrict__ boffs) {
    int idx = blockIdx.x * 256 + threadIdx.x;
    if (idx < NN) prefix[idx] += boffs[idx >> 10];
}

// ---------------- attention KL loss + ratio ----------------
__global__ void k_kl(const float* __restrict__ score2, const float* __restrict__ keep2,
                     const int* __restrict__ prefix, const float* __restrict__ natt,
                     const int* __restrict__ offs, float* __restrict__ out_loss,
                     float* __restrict__ c_total) {
    int b = blockIdx.x, tid = threadIdx.x;
    int s0 = offs[b], s1 = offs[b + 1];
    float s = 0.f, c = 0.f;
    for (int i = s0 + tid; i < s1; i += 256) {
        if (keep2[i] > 0.f) {
            int r1 = prefix[i] - 1;
            r1 = max(0, min(r1, NN - 1));
            float t = natt[r1];
            float logp = logf(score2[i] + 1e-14f);
            float kl = ((t > 0.f) ? t * logf(fmaxf(t, 1e-38f)) : 0.f) - t * logp;
            s += kl; c += 1.f;
        }
    }
    __shared__ float rs[256], rc[256];
    rs[tid] = s; rc[tid] = c; __syncthreads();
    for (int o = 128; o > 0; o >>= 1) {
        if (tid < o) { rs[tid] += rs[tid + o]; rc[tid] += rc[tid + o]; }
        __syncthreads();
    }
    if (tid == 0) {
        out_loss[b] = rs[0] / fmaxf(rc[0], 1.f);
        atomicAdd(c_total, rc[0]);
    }
}
__global__ void k_final(const float* __restrict__ c_total, float* __restrict__ out) {
    out[0] = c_total[0] / (float)NN;
}

extern "C" void kernel_launch(void* const* d_in, const int* in_sizes, int n_in,
                              void* d_out, int out_size, void* d_ws, size_t ws_size,
                              hipStream_t stream) {
    const float* x    = (const float*)d_in[0];
    const int*   src  = (const int*)d_in[1];
    const int*   dst  = (const int*)d_in[2];
    const int*   batch= (const int*)d_in[3];
    const float* natt = (const float*)d_in[4];
    const float* W11 = (const float*)d_in[5],  *b11 = (const float*)d_in[6];
    const float* W12 = (const float*)d_in[7],  *b12 = (const float*)d_in[8];
    const float* gW1 = (const float*)d_in[9],  *gb1 = (const float*)d_in[10];
    const float* W21 = (const float*)d_in[11], *b21 = (const float*)d_in[12];
    const float* W22 = (const float*)d_in[13], *b22 = (const float*)d_in[14];
    const float* gW2 = (const float*)d_in[15], *gb2 = (const float*)d_in[16];
    const float* W31 = (const float*)d_in[17], *b31 = (const float*)d_in[18];
    const float* W32 = (const float*)d_in[19], *b32 = (const float*)d_in[20];
    const float* Wl  = (const float*)d_in[21], *bl  = (const float*)d_in[22];
    float* out = (float*)d_out;

    // workspace layout
    float* hA     = (float*)d_ws;                 // N*64  (reused as h3)
    float* hB     = hA + (size_t)NN * 64;         // N*64
    float* ybuf   = hB + (size_t)NN * 64;         // N*64  (CSR build: H/Hs live here first)
    float* zbuf   = ybuf + (size_t)NN * 64;       // N*64  (CSR build: ebuf lives here first)
    float* hwd    = zbuf + (size_t)NN * 64;       // N
    float* dinv   = hwd + NN;                     // N
    float* attn   = dinv + NN;                    // N
    float* score1 = attn + NN;                    // N
    float* keep1  = score1 + NN;                  // N
    float* sk1    = keep1 + NN;                   // N
    float* score2 = sk1 + NN;                     // N
    float* keep2  = score2 + NN;                  // N
    float* sk2    = keep2 + NN;                   // N
    int*   prefix = (int*)(sk2 + NN);             // N
    int*   cnt    = prefix + NN;                  // N
    int*   roffs  = cnt + NN;                     // N+1
    int*   csrc   = roffs + NN + 1;               // E
    int*   offs   = csrc + NE;                    // B+1
    int*   bsums  = offs + NB + 1;                // 128
    float* c_total= (float*)(bsums + 128);        // 1
    // CSR-build scratch aliases (dead regions during build)
    int*   H      = (int*)ybuf;                   // NBKT*P_SORT
    int*   Hs     = H + HLEN;                     // NBKT*P_SORT
    int2*  ebuf   = (int2*)zbuf;                  // E pairs (12.8 MB <= 25.6 MB region)

    const int nblk_n  = (NN + 255) / 256;
    const int nblk_n8 = NN / 8;

    // graph offsets (batch sorted -> binary search)
    k_offs_bs<<<2, 256, 0, stream>>>(batch, offs);

    // CSR by dst: coarse hist -> scan -> pair scatter -> per-bucket LDS CSR
    k_hist_coarse<<<P_SORT, 256, 0, stream>>>(dst, H);
    k_iscan_blk<<<HSCAN_BLK, 256, 0, stream>>>(H, Hs, bsums, HLEN);
    k_iscan_mid<<<1, 1, 0, stream>>>(bsums, HSCAN_BLK);
    k_iscan_add<<<(HLEN + 255) / 256, 256, 0, stream>>>(Hs, bsums, HLEN);
    k_scatter_pairs<<<P_SORT, 256, 0, stream>>>(src, dst, Hs, ebuf);
    k_bucket_csr<<<NBKT, 256, 0, stream>>>(ebuf, Hs, roffs, csrc);

    // ---- GIN1: pre-GEMM + pure gather + post ----
    k_pre1_g<<<GVB, 256, 0, stream>>>(x, W11, ybuf);
    k_gather_y<<<nblk_n8, 256, 0, stream>>>(ybuf, roffs, csrc, nullptr, nullptr, zbuf, nullptr);
    k_post_g<<<GVB, 256, 0, stream>>>(zbuf, b11, W12, b12, gW1, roffs, nullptr, nullptr,
                                      hA, hwd, dinv, 1);
    k_attn<<<nblk_n, 256, 0, stream>>>(roffs, csrc, hwd, dinv, gb1, attn);
    k_softmax_pool<<<NB, 256, 0, stream>>>(attn, nullptr, offs, score1, keep1, sk1);

    // ---- GIN2 ----
    k_pre23_g<<<GVB, 256, 0, stream>>>(hA, sk1, W21, ybuf);
    k_gather_y<<<nblk_n8, 256, 0, stream>>>(ybuf, roffs, csrc, keep1, sk1, zbuf, cnt);
    k_post_g<<<GVB, 256, 0, stream>>>(zbuf, b21, W22, b22, gW2, roffs, cnt, keep1,
                                      hB, hwd, dinv, 2);
    k_attn<<<nblk_n, 256, 0, stream>>>(roffs, csrc, hwd, dinv, gb2, attn);
    k_softmax_pool<<<NB, 256, 0, stream>>>(attn, keep1, offs, score2, keep2, sk2);

    // ---- GIN3 (h3 written into hA buffer) ----
    k_pre23_g<<<GVB, 256, 0, stream>>>(hB, sk2, W31, ybuf);
    k_gather_y<<<nblk_n8, 256, 0, stream>>>(ybuf, roffs, csrc, keep2, nullptr, zbuf, nullptr);
    k_post_g<<<GVB, 256, 0, stream>>>(zbuf, b31, W32, b32, nullptr, roffs, nullptr, nullptr,
                                      hA, nullptr, nullptr, 3);

    // ---- head: global max pool + linear ----
    k_gmax_linear<<<NB, 256, 0, stream>>>(hA, keep2, offs, Wl, bl, out);

    // ---- attention KL loss + ratio ----
    k_scan1<<<NSCAN_BLK, 256, 0, stream>>>(keep1, prefix, bsums);
    k_iscan_mid<<<1, 1, 0, stream>>>(bsums, NSCAN_BLK);
    k_scan3<<<nblk_n, 256, 0, stream>>>(prefix, bsums);
    hipMemsetAsync(c_total, 0, sizeof(float), stream);
    k_kl<<<NB, 256, 0, stream>>>(score2, keep2, prefix, natt, offs, out + NB, c_total);
    k_final<<<1, 1, 0, stream>>>(c_total, out + 2 * NB);
}

// Round 10
// 587.757 us; speedup vs baseline: 10.9203x; 1.0754x over previous
//
#include <hip/hip_runtime.h>
#include <hip/hip_fp16.h>
#include <math.h>

#define NN 100000
#define NE 1600000
#define NB 256
#define NEGF (-1e30f)
#define NSCAN_BLK ((NN + 1023) / 1024)
#define GVB 1024            // grid-stride GEMV blocks
#define P_SORT 256          // blocks in coarse histogram/scatter
#define NBKT 391            // ceil(NN/256) coarse buckets (dst>>8)
#define HLEN (NBKT * P_SORT)
#define HSCAN_BLK ((HLEN + 1023) / 1024)
#define BKT_CAP 6144        // LDS staging ints (24 KB); avg bucket = 4096 edges

__device__ __forceinline__ float rlane(float v, int k) {
    return __int_as_float(__builtin_amdgcn_readlane(__float_as_int(v), k));
}

// ---------------- graph offsets via binary search (batch is sorted) ----------------
__global__ void k_offs_bs(const int* __restrict__ batch, int* __restrict__ offs) {
    int g = blockIdx.x * 256 + threadIdx.x;
    if (g > NB) return;
    int lo = 0, hi = NN;
    while (lo < hi) { int mid = (lo + hi) >> 1; if (batch[mid] < g) lo = mid + 1; else hi = mid; }
    offs[g] = lo;
}

// ---------------- CSR build: two-level counting sort ----------------
__global__ void k_hist_coarse(const int* __restrict__ dst, int* __restrict__ H) {
    __shared__ int lh[NBKT];
    int p = blockIdx.x, tid = threadIdx.x;
    for (int i = tid; i < NBKT; i += 256) lh[i] = 0;
    __syncthreads();
    int c0 = p * (NE / P_SORT), c1 = c0 + NE / P_SORT;
    for (int i = c0 + tid; i < c1; i += 256) atomicAdd(&lh[dst[i] >> 8], 1);
    __syncthreads();
    for (int i = tid; i < NBKT; i += 256) H[i * P_SORT + p] = lh[i];
}
__global__ void k_iscan_blk(const int* __restrict__ in, int* __restrict__ pref,
                            int* __restrict__ bsums, int len) {
    int blk = blockIdx.x, tid = threadIdx.x;
    int base = blk * 1024;
    int vals[4], tsum = 0;
    for (int j = 0; j < 4; ++j) {
        int idx = base + tid * 4 + j;
        int v = (idx < len) ? in[idx] : 0;
        vals[j] = tsum; tsum += v;               // exclusive within thread
    }
    __shared__ int sh[256];
    sh[tid] = tsum; __syncthreads();
    for (int o = 1; o < 256; o <<= 1) {
        int v = (tid >= o) ? sh[tid - o] : 0;
        __syncthreads();
        sh[tid] += v;
        __syncthreads();
    }
    int excl = sh[tid] - tsum;
    for (int j = 0; j < 4; ++j) {
        int idx = base + tid * 4 + j;
        if (idx < len) pref[idx] = excl + vals[j];
    }
    if (tid == 255) bsums[blk] = sh[255];
}
__global__ void k_iscan_mid(int* __restrict__ bsums, int nb) {
    int acc = 0;
    for (int i = 0; i < nb; ++i) { int v = bsums[i]; bsums[i] = acc; acc += v; }
}
__global__ void k_iscan_add(int* __restrict__ pref, const int* __restrict__ bsums, int len) {
    int idx = blockIdx.x * 256 + threadIdx.x;
    if (idx < len) pref[idx] += bsums[idx >> 10];
}
__global__ void k_scatter_pairs(const int* __restrict__ src, const int* __restrict__ dst,
                                const int* __restrict__ Hs, int2* __restrict__ ebuf) {
    __shared__ int curs[NBKT];
    int p = blockIdx.x, tid = threadIdx.x;
    for (int i = tid; i < NBKT; i += 256) curs[i] = Hs[i * P_SORT + p];
    __syncthreads();
    int c0 = p * (NE / P_SORT), c1 = c0 + NE / P_SORT;
    for (int i = c0 + tid; i < c1; i += 256) {
        int d = dst[i];
        int pos = atomicAdd(&curs[d >> 8], 1);
        ebuf[pos] = make_int2(src[i], d);
    }
}
__global__ void k_bucket_csr(const int2* __restrict__ ebuf, const int* __restrict__ Hs,
                             int* __restrict__ roffs, int* __restrict__ csrc) {
    __shared__ int hist2[256];
    __shared__ int curs2[256];
    __shared__ int sh[256];
    __shared__ int stage[BKT_CAP];
    int b = blockIdx.x, tid = threadIdx.x;
    int e0 = Hs[b * P_SORT];
    int e1 = (b + 1 < NBKT) ? Hs[(b + 1) * P_SORT] : NE;
    int n0 = b * 256;
    int cntb = e1 - e0;
    if (b == 0 && tid == 0) roffs[NN] = NE;
    hist2[tid] = 0;
    __syncthreads();
    for (int i = e0 + tid; i < e1; i += 256) atomicAdd(&hist2[ebuf[i].y & 255], 1);
    __syncthreads();
    int v = hist2[tid];
    sh[tid] = v; __syncthreads();
    for (int o = 1; o < 256; o <<= 1) {
        int u = (tid >= o) ? sh[tid - o] : 0;
        __syncthreads();
        sh[tid] += u;
        __syncthreads();
    }
    int excl = sh[tid] - v;
    int node = n0 + tid;
    if (node < NN) roffs[node] = e0 + excl;
    curs2[tid] = excl;
    __syncthreads();
    if (cntb <= BKT_CAP) {
        for (int i = e0 + tid; i < e1; i += 256) {
            int2 pr = ebuf[i];
            int pos = atomicAdd(&curs2[pr.y & 255], 1);
            stage[pos] = pr.x;
        }
        __syncthreads();
        for (int i = tid; i < cntb; i += 256) csrc[e0 + i] = stage[i];
    } else {
        for (int i = e0 + tid; i < e1; i += 256) {
            int2 pr = ebuf[i];
            int pos = atomicAdd(&curs2[pr.y & 255], 1);
            csrc[e0 + pos] = pr.x;
        }
    }
}

// ---------------- GEMV kernels: W column in VGPRs, grid-stride over node tiles ----------------
__global__ __launch_bounds__(256, 1) void k_pre1_g(const float* __restrict__ x,
                                                   const float* __restrict__ W,
                                                   float* __restrict__ y) {
    int tid = threadIdx.x, w = tid >> 6, l = tid & 63;
    float Wc[128];
#pragma unroll
    for (int k = 0; k < 128; ++k) Wc[k] = W[k * 64 + l];
    int g = blockIdx.x * 4 + w;
    const int G = GVB * 4;
    for (int t = g; t < NN / 4; t += G) {
        int n0 = t * 4;
        float in0[4], in1[4], acc[4];
#pragma unroll
        for (int r = 0; r < 4; ++r) {
            in0[r] = x[(size_t)(n0 + r) * 128 + l];
            in1[r] = x[(size_t)(n0 + r) * 128 + 64 + l];
            acc[r] = 0.f;
        }
#pragma unroll
        for (int k = 0; k < 64; ++k)
#pragma unroll
            for (int r = 0; r < 4; ++r) acc[r] = fmaf(rlane(in0[r], k), Wc[k], acc[r]);
#pragma unroll
        for (int k = 0; k < 64; ++k)
#pragma unroll
            for (int r = 0; r < 4; ++r) acc[r] = fmaf(rlane(in1[r], k), Wc[64 + k], acc[r]);
#pragma unroll
        for (int r = 0; r < 4; ++r) y[(size_t)(n0 + r) * 64 + l] = acc[r];
    }
}

// pre for GIN2/3: y = (h * sk) @ W, emitted in fp16 (consumed by fp16 gather)
__global__ __launch_bounds__(256) void k_pre23_h(const float* __restrict__ h,
                                                 const float* __restrict__ sk,
                                                 const float* __restrict__ W,
                                                 __half* __restrict__ yh) {
    int tid = threadIdx.x, w = tid >> 6, l = tid & 63;
    float Wc[64];
#pragma unroll
    for (int k = 0; k < 64; ++k) Wc[k] = W[k * 64 + l];
    int g = blockIdx.x * 4 + w;
    const int G = GVB * 4;
    for (int t = g; t < NN / 8; t += G) {
        int n0 = t * 8;
        float in[8], acc[8];
#pragma unroll
        for (int r = 0; r < 8; ++r) {
            in[r] = h[(size_t)(n0 + r) * 64 + l] * sk[n0 + r];
            acc[r] = 0.f;
        }
#pragma unroll
        for (int k = 0; k < 64; ++k)
#pragma unroll
            for (int r = 0; r < 8; ++r) acc[r] = fmaf(rlane(in[r], k), Wc[k], acc[r]);
#pragma unroll
        for (int r = 0; r < 8; ++r) yh[(size_t)(n0 + r) * 64 + l] = __float2half(acc[r]);
    }
}

// post: h = relu(relu(z+b1)@W2 + b2) [+ score-dot + dinv epilogue]
__global__ __launch_bounds__(256) void k_post_g(const float* __restrict__ z,
                                                const float* __restrict__ b1,
                                                const float* __restrict__ W2,
                                                const float* __restrict__ b2,
                                                const float* __restrict__ gW,
                                                const int* __restrict__ roffs,
                                                const int* __restrict__ cnt,
                                                const float* __restrict__ keep,
                                                float* __restrict__ hOut,
                                                float* __restrict__ hwd,
                                                float* __restrict__ dinv, int mode) {
    int tid = threadIdx.x, w = tid >> 6, l = tid & 63;
    float Wc[64];
#pragma unroll
    for (int k = 0; k < 64; ++k) Wc[k] = W2[k * 64 + l];
    float b1v = b1[l], b2v = b2[l];
    float gWv = (mode < 3) ? gW[l] : 0.f;
    int g = blockIdx.x * 4 + w;
    const int G = GVB * 4;
    for (int t = g; t < NN / 8; t += G) {
        int n0 = t * 8;
        float in[8], acc[8];
#pragma unroll
        for (int r = 0; r < 8; ++r) {
            in[r] = fmaxf(z[(size_t)(n0 + r) * 64 + l] + b1v, 0.f);
            acc[r] = b2v;
        }
#pragma unroll
        for (int k = 0; k < 64; ++k)
#pragma unroll
            for (int r = 0; r < 8; ++r) acc[r] = fmaf(rlane(in[r], k), Wc[k], acc[r]);
#pragma unroll
        for (int r = 0; r < 8; ++r) {
            acc[r] = fmaxf(acc[r], 0.f);
            hOut[(size_t)(n0 + r) * 64 + l] = acc[r];
        }
        if (mode < 3) {
#pragma unroll
            for (int r = 0; r < 8; ++r) {
                float t2 = acc[r] * gWv;
                for (int o = 32; o > 0; o >>= 1) t2 += __shfl_down(t2, o, 64);
                if (l == 0) {
                    int n = n0 + r;
                    float di;
                    if (mode == 1) di = 1.f / sqrtf((float)(roffs[n + 1] - roffs[n]) + 1.f);
                    else di = (keep[n] != 0.f) ? 1.f / sqrtf((float)cnt[n] + 1.f) : 0.f;
                    dinv[n] = di;
                    hwd[n] = t2 * di;
                }
            }
        }
    }
}

// ---------------- fp32 CSR gather (GIN1), unroll-4 ----------------
__global__ void k_gather_y(const float* __restrict__ y, const int* __restrict__ roffs,
                           const int* __restrict__ csrc, float* __restrict__ z) {
    int tid = threadIdx.x;
    int d = blockIdx.x * 8 + (tid >> 5);
    int l = tid & 31;
    const float2* y2 = (const float2*)y;
    float2 acc = y2[(size_t)d * 32 + l];            // self term
    int e0 = roffs[d], e1 = roffs[d + 1];
    int e = e0;
    for (; e + 3 < e1; e += 4) {
        int s0 = csrc[e], s1 = csrc[e + 1], s2 = csrc[e + 2], s3 = csrc[e + 3];
        float2 v0 = y2[(size_t)s0 * 32 + l];
        float2 v1 = y2[(size_t)s1 * 32 + l];
        float2 v2 = y2[(size_t)s2 * 32 + l];
        float2 v3 = y2[(size_t)s3 * 32 + l];
        acc.x += (v0.x + v1.x) + (v2.x + v3.x);
        acc.y += (v0.y + v1.y) + (v2.y + v3.y);
    }
    for (; e < e1; ++e) {
        float2 v0 = y2[(size_t)csrc[e] * 32 + l];
        acc.x += v0.x; acc.y += v0.y;
    }
    ((float2*)z)[(size_t)d * 32 + l] = acc;
}

// ---------------- fp16 CSR gather (GIN2/GIN3), unroll-4, optional kept-count ----------------
__global__ void k_gather_h(const __half* __restrict__ yh, const int* __restrict__ roffs,
                           const int* __restrict__ csrc, const float* __restrict__ keepd,
                           const float* __restrict__ sk, float* __restrict__ z,
                           int* __restrict__ cnt) {
    int tid = threadIdx.x;
    int d = blockIdx.x * 8 + (tid >> 5);
    int l = tid & 31;
    const __half2* y2 = (const __half2*)yh;
    __half2 sv = y2[(size_t)d * 32 + l];
    float2 acc = make_float2(__low2float(sv), __high2float(sv));   // self term
    int c = 0;
    if (!keepd || keepd[d] != 0.f) {                // dst-side gate (wave-uniform)
        int e0 = roffs[d], e1 = roffs[d + 1];
        int e = e0;
        for (; e + 3 < e1; e += 4) {
            int s0 = csrc[e], s1 = csrc[e + 1], s2 = csrc[e + 2], s3 = csrc[e + 3];
            __half2 v0 = y2[(size_t)s0 * 32 + l];
            __half2 v1 = y2[(size_t)s1 * 32 + l];
            __half2 v2 = y2[(size_t)s2 * 32 + l];
            __half2 v3 = y2[(size_t)s3 * 32 + l];
            acc.x += (__low2float(v0) + __low2float(v1)) + (__low2float(v2) + __low2float(v3));
            acc.y += (__high2float(v0) + __high2float(v1)) + (__high2float(v2) + __high2float(v3));
            if (sk) c += (sk[s0] > 0.f) + (sk[s1] > 0.f) + (sk[s2] > 0.f) + (sk[s3] > 0.f);
        }
        for (; e < e1; ++e) {
            int s0 = csrc[e];
            __half2 v0 = y2[(size_t)s0 * 32 + l];
            acc.x += __low2float(v0); acc.y += __high2float(v0);
            if (sk) c += (sk[s0] > 0.f);
        }
    }
    ((float2*)z)[(size_t)d * 32 + l] = acc;
    if (cnt && l == 0) cnt[d] = c;
}

// ---------------- attention gather: attn[i] = dinv[i]*(sum_nbr hwd + hwd[i]) + gb ----------------
__global__ void k_attn(const int* __restrict__ roffs, const int* __restrict__ csrc,
                       const float* __restrict__ hwd, const float* __restrict__ dinv,
                       const float* __restrict__ gb, float* __restrict__ attn) {
    int i = blockIdx.x * 256 + threadIdx.x;
    if (i >= NN) return;
    float sum = hwd[i];
    int e0 = roffs[i], e1 = roffs[i + 1];
    for (int e = e0; e < e1; ++e) sum += hwd[csrc[e]];
    attn[i] = dinv[i] * sum + gb[0];
}

// ---------------- per-graph softmax + threshold; also emits sk = score*keep ----------------
__global__ void k_softmax_pool(const float* __restrict__ attn, const float* __restrict__ nmask,
                               const int* __restrict__ offs, float* __restrict__ score,
                               float* __restrict__ keep, float* __restrict__ sk) {
    int b = blockIdx.x, tid = threadIdx.x;
    int s0 = offs[b], s1 = offs[b + 1];
    __shared__ float red[256];
    float m = NEGF;
    for (int i = s0 + tid; i < s1; i += 256) {
        float nm = nmask ? nmask[i] : 1.f;
        if (nm > 0.f) m = fmaxf(m, attn[i]);
    }
    red[tid] = m; __syncthreads();
    for (int o = 128; o > 0; o >>= 1) { if (tid < o) red[tid] = fmaxf(red[tid], red[tid + o]); __syncthreads(); }
    m = red[0]; __syncthreads();
    float s = 0.f;
    for (int i = s0 + tid; i < s1; i += 256) {
        float nm = nmask ? nmask[i] : 1.f;
        if (nm > 0.f) s += expf(attn[i] - m);
    }
    red[tid] = s; __syncthreads();
    for (int o = 128; o > 0; o >>= 1) { if (tid < o) red[tid] += red[tid + o]; __syncthreads(); }
    s = red[0]; __syncthreads();
    float sden = fmaxf(s, 1e-30f);
    float smax = NEGF;
    for (int i = s0 + tid; i < s1; i += 256) {
        float nm = nmask ? nmask[i] : 1.f;
        float sc = (nm > 0.f) ? expf(attn[i] - m) / sden : 0.f;
        score[i] = sc;
        smax = fmaxf(smax, (nm > 0.f) ? sc : NEGF);
    }
    red[tid] = smax; __syncthreads();
    for (int o = 128; o > 0; o >>= 1) { if (tid < o) red[tid] = fmaxf(red[tid], red[tid + o]); __syncthreads(); }
    smax = red[0]; __syncthreads();
    float thr = fminf(1e-3f, smax - 1e-7f);
    for (int i = s0 + tid; i < s1; i += 256) {
        float nm = nmask ? nmask[i] : 1.f;
        float sc = score[i];
        float kp = (nm > 0.f && sc > thr) ? 1.f : 0.f;
        keep[i] = kp;
        sk[i] = sc * kp;
    }
}

// ---------------- output head ----------------
__global__ void k_gmax_linear(const float* __restrict__ h, const float* __restrict__ keep2,
                              const int* __restrict__ offs, const float* __restrict__ Wl,
                              const float* __restrict__ bl, float* __restrict__ out) {
    int b = blockIdx.x, tid = threadIdx.x;
    int s0 = offs[b], s1 = offs[b + 1];
    int f = tid & 63, g = tid >> 6;
    float m = NEGF;
    for (int i = s0 + g; i < s1; i += 4)
        if (keep2[i] > 0.f) m = fmaxf(m, h[(size_t)i * 64 + f]);
    __shared__ float red[256];
    red[tid] = m; __syncthreads();
    if (g == 0) {
        m = fmaxf(fmaxf(red[f], red[64 + f]), fmaxf(red[128 + f], red[192 + f]));
        float v = m * Wl[f];
        for (int o = 32; o > 0; o >>= 1) v += __shfl_down(v, o, 64);
        if (f == 0) out[b] = v + bl[0];
    }
}

// ---------------- prefix sum of keep1 (exact int) ----------------
__global__ void k_scan1(const float* __restrict__ keep1, int* __restrict__ prefix,
                        int* __restrict__ bsums) {
    int blk = blockIdx.x, tid = threadIdx.x;
    int base = blk * 1024;
    int vals[4], tsum = 0;
    for (int j = 0; j < 4; ++j) {
        int idx = base + tid * 4 + j;
        int v = (idx < NN && keep1[idx] > 0.f) ? 1 : 0;
        tsum += v; vals[j] = tsum;
    }
    __shared__ int sh[256];
    sh[tid] = tsum; __syncthreads();
    for (int o = 1; o < 256; o <<= 1) {
        int v = (tid >= o) ? sh[tid - o] : 0;
        __syncthreads();
        sh[tid] += v;
        __syncthreads();
    }
    int excl = sh[tid] - tsum;
    for (int j = 0; j < 4; ++j) {
        int idx = base + tid * 4 + j;
        if (idx < NN) prefix[idx] = excl + vals[j];
    }
    if (tid == 255) bsums[blk] = sh[255];
}
__global__ void k_scan3(int* __restrict__ prefix, const int* __restrict__ boffs) {
    int idx = blockIdx.x * 256 + threadIdx.x;
    if (idx < NN) prefix[idx] += boffs[idx >> 10];
}

// ---------------- attention KL loss + ratio ----------------
__global__ void k_kl(const float* __restrict__ score2, const float* __restrict__ keep2,
                     const int* __restrict__ prefix, const float* __restrict__ natt,
                     const int* __restrict__ offs, float* __restrict__ out_loss,
                     float* __restrict__ c_total) {
    int b = blockIdx.x, tid = threadIdx.x;
    int s0 = offs[b], s1 = offs[b + 1];
    float s = 0.f, c = 0.f;
    for (int i = s0 + tid; i < s1; i += 256) {
        if (keep2[i] > 0.f) {
            int r1 = prefix[i] - 1;
            r1 = max(0, min(r1, NN - 1));
            float t = natt[r1];
            float logp = logf(score2[i] + 1e-14f);
            float kl = ((t > 0.f) ? t * logf(fmaxf(t, 1e-38f)) : 0.f) - t * logp;
            s += kl; c += 1.f;
        }
    }
    __shared__ float rs[256], rc[256];
    rs[tid] = s; rc[tid] = c; __syncthreads();
    for (int o = 128; o > 0; o >>= 1) {
        if (tid < o) { rs[tid] += rs[tid + o]; rc[tid] += rc[tid + o]; }
        __syncthreads();
    }
    if (tid == 0) {
        out_loss[b] = rs[0] / fmaxf(rc[0], 1.f);
        atomicAdd(c_total, rc[0]);
    }
}
__global__ void k_final(const float* __restrict__ c_total, float* __restrict__ out) {
    out[0] = c_total[0] / (float)NN;
}

extern "C" void kernel_launch(void* const* d_in, const int* in_sizes, int n_in,
                              void* d_out, int out_size, void* d_ws, size_t ws_size,
                              hipStream_t stream) {
    const float* x    = (const float*)d_in[0];
    const int*   src  = (const int*)d_in[1];
    const int*   dst  = (const int*)d_in[2];
    const int*   batch= (const int*)d_in[3];
    const float* natt = (const float*)d_in[4];
    const float* W11 = (const float*)d_in[5],  *b11 = (const float*)d_in[6];
    const float* W12 = (const float*)d_in[7],  *b12 = (const float*)d_in[8];
    const float* gW1 = (const float*)d_in[9],  *gb1 = (const float*)d_in[10];
    const float* W21 = (const float*)d_in[11], *b21 = (const float*)d_in[12];
    const float* W22 = (const float*)d_in[13], *b22 = (const float*)d_in[14];
    const float* gW2 = (const float*)d_in[15], *gb2 = (const float*)d_in[16];
    const float* W31 = (const float*)d_in[17], *b31 = (const float*)d_in[18];
    const float* W32 = (const float*)d_in[19], *b32 = (const float*)d_in[20];
    const float* Wl  = (const float*)d_in[21], *bl  = (const float*)d_in[22];
    float* out = (float*)d_out;

    // workspace layout
    float* hA     = (float*)d_ws;                 // N*64  (reused as h3)
    float* hB     = hA + (size_t)NN * 64;         // N*64
    float* ybuf   = hB + (size_t)NN * 64;         // N*64  (CSR build: H/Hs live here first; fp16 y aliases)
    float* zbuf   = ybuf + (size_t)NN * 64;       // N*64  (CSR build: ebuf lives here first)
    float* hwd    = zbuf + (size_t)NN * 64;       // N
    float* dinv   = hwd + NN;                     // N
    float* attn   = dinv + NN;                    // N
    float* score1 = attn + NN;                    // N
    float* keep1  = score1 + NN;                  // N
    float* sk1    = keep1 + NN;                   // N
    float* score2 = sk1 + NN;                     // N
    float* keep2  = score2 + NN;                  // N
    float* sk2    = keep2 + NN;                   // N
    int*   prefix = (int*)(sk2 + NN);             // N
    int*   cnt    = prefix + NN;                  // N
    int*   roffs  = cnt + NN;                     // N+1
    int*   csrc   = roffs + NN + 1;               // E
    int*   offs   = csrc + NE;                    // B+1
    int*   bsums  = offs + NB + 1;                // 128
    float* c_total= (float*)(bsums + 128);        // 1
    // CSR-build scratch aliases (dead regions during build)
    int*   H      = (int*)ybuf;                   // NBKT*P_SORT
    int*   Hs     = H + HLEN;                     // NBKT*P_SORT
    int2*  ebuf   = (int2*)zbuf;                  // E pairs (12.8 MB <= 25.6 MB region)
    __half* yh    = (__half*)ybuf;                // fp16 y for GIN2/3 (12.8 MB <= 25.6 MB)

    const int nblk_n  = (NN + 255) / 256;
    const int nblk_n8 = NN / 8;

    // graph offsets (batch sorted -> binary search)
    k_offs_bs<<<2, 256, 0, stream>>>(batch, offs);

    // CSR by dst: coarse hist -> scan -> pair scatter -> per-bucket LDS CSR
    k_hist_coarse<<<P_SORT, 256, 0, stream>>>(dst, H);
    k_iscan_blk<<<HSCAN_BLK, 256, 0, stream>>>(H, Hs, bsums, HLEN);
    k_iscan_mid<<<1, 1, 0, stream>>>(bsums, HSCAN_BLK);
    k_iscan_add<<<(HLEN + 255) / 256, 256, 0, stream>>>(Hs, bsums, HLEN);
    k_scatter_pairs<<<P_SORT, 256, 0, stream>>>(src, dst, Hs, ebuf);
    k_bucket_csr<<<NBKT, 256, 0, stream>>>(ebuf, Hs, roffs, csrc);

    // ---- GIN1: pre-GEMM (fp32) + pure gather (fp32) + post ----
    k_pre1_g<<<GVB, 256, 0, stream>>>(x, W11, ybuf);
    k_gather_y<<<nblk_n8, 256, 0, stream>>>(ybuf, roffs, csrc, zbuf);
    k_post_g<<<GVB, 256, 0, stream>>>(zbuf, b11, W12, b12, gW1, roffs, nullptr, nullptr,
                                      hA, hwd, dinv, 1);
    k_attn<<<nblk_n, 256, 0, stream>>>(roffs, csrc, hwd, dinv, gb1, attn);
    k_softmax_pool<<<NB, 256, 0, stream>>>(attn, nullptr, offs, score1, keep1, sk1);

    // ---- GIN2 (fp16 gather payload) ----
    k_pre23_h<<<GVB, 256, 0, stream>>>(hA, sk1, W21, yh);
    k_gather_h<<<nblk_n8, 256, 0, stream>>>(yh, roffs, csrc, keep1, sk1, zbuf, cnt);
    k_post_g<<<GVB, 256, 0, stream>>>(zbuf, b21, W22, b22, gW2, roffs, cnt, keep1,
                                      hB, hwd, dinv, 2);
    k_attn<<<nblk_n, 256, 0, stream>>>(roffs, csrc, hwd, dinv, gb2, attn);
    k_softmax_pool<<<NB, 256, 0, stream>>>(attn, keep1, offs, score2, keep2, sk2);

    // ---- GIN3 (fp16 gather payload; h3 written into hA buffer) ----
    k_pre23_h<<<GVB, 256, 0, stream>>>(hB, sk2, W31, yh);
    k_gather_h<<<nblk_n8, 256, 0, stream>>>(yh, roffs, csrc, keep2, nullptr, zbuf, nullptr);
    k_post_g<<<GVB, 256, 0, stream>>>(zbuf, b31, W32, b32, nullptr, roffs, nullptr, nullptr,
                                      hA, nullptr, nullptr, 3);

    // ---- head: global max pool + linear ----
    k_gmax_linear<<<NB, 256, 0, stream>>>(hA, keep2, offs, Wl, bl, out);

    // ---- attention KL loss + ratio ----
    k_scan1<<<NSCAN_BLK, 256, 0, stream>>>(keep1, prefix, bsums);
    k_iscan_mid<<<1, 1, 0, stream>>>(bsums, NSCAN_BLK);
    k_scan3<<<nblk_n, 256, 0, stream>>>(prefix, bsums);
    hipMemsetAsync(c_total, 0, sizeof(float), stream);
    k_kl<<<NB, 256, 0, stream>>>(score2, keep2, prefix, natt, offs, out + NB, c_total);
    k_final<<<1, 1, 0, stream>>>(c_total, out + 2 * NB);
}